// Round 6
// baseline (1546.330 us; speedup 1.0000x reference)
//
#include <hip/hip_runtime.h>

#define NEG_SLOPE 0.01f
#define CSHIFT 11               // 2048 rows per coarse bucket (<=196 buckets for N<=400k)
#define RPB (1 << CSHIFT)       // rows per bucket
#define TILE_E 2048             // edges per split tile

typedef _Float16 half_t;
typedef _Float16 half2_t __attribute__((ext_vector_type(2)));
typedef _Float16 half4_t __attribute__((ext_vector_type(4)));

static inline int cdiv(long long a, long long b) { return (int)((a + b - 1) / b); }

__global__ __launch_bounds__(256) void zero_i32(int* __restrict__ p, int n) {
    int i = blockIdx.x * 256 + threadIdx.x;
    if (i < n) p[i] = 0;
}

// ---- coarse histogram: LDS counters (<=196 buckets), one merge atomic per (block,bucket) ----
__global__ __launch_bounds__(256) void hist_coarse(const int* __restrict__ rows, int* __restrict__ ccnt, int E) {
    __shared__ int cnt[256];
    int t = threadIdx.x;
    cnt[t] = 0;
    __syncthreads();
    int base = blockIdx.x * TILE_E;
#pragma unroll
    for (int k = 0; k < TILE_E / 256; k++) {
        int e = base + k * 256 + t;
        if (e < E) atomicAdd(&cnt[rows[e] >> CSHIFT], 1);
    }
    __syncthreads();
    if (cnt[t] > 0) atomicAdd(&ccnt[t], cnt[t]);
}

__global__ void scan_coarse(const int* __restrict__ ccnt, int* __restrict__ cbase,
                            int* __restrict__ cfront, int NBc, int E) {
    if (threadIdx.x == 0 && blockIdx.x == 0) {
        int run = 0;
        for (int b = 0; b < NBc; b++) { cbase[b] = run; cfront[b] = run; run += ccnt[b]; }
        cbase[NBc] = E;
    }
}

// ---- pass A: LDS multisplit into coarse buckets; dense chunk writes ----
// record: ( (row & 2047) << 19 | col , val )   [11+19 = 30 bits, col < 2^19]
__global__ __launch_bounds__(256) void split_coarse(
    const int* __restrict__ rows, const int* __restrict__ cols, const float* __restrict__ vals,
    int* __restrict__ cfront, int2* __restrict__ stg1, int E)
{
    __shared__ int cnt[256], gb[256];
    int t = threadIdx.x;
    cnt[t] = 0;
    __syncthreads();
    int base = blockIdx.x * TILE_E;
    int myb[8], myrank[8]; int2 mycv[8];
#pragma unroll
    for (int k = 0; k < 8; k++) {
        int e = base + k * 256 + t;
        myb[k] = -1;
        if (e < E) {
            int r = rows[e];
            int b = r >> CSHIFT;
            mycv[k] = make_int2((int)(((unsigned)(r & (RPB - 1)) << 19) | (unsigned)cols[e]),
                                __float_as_int(vals[e]));
            myb[k] = b;
            myrank[k] = atomicAdd(&cnt[b], 1);
        }
    }
    __syncthreads();
    if (cnt[t] > 0) gb[t] = atomicAdd(&cfront[t], cnt[t]);
    __syncthreads();
#pragma unroll
    for (int k = 0; k < 8; k++)
        if (myb[k] >= 0) stg1[gb[myb[k]] + myrank[k]] = mycv[k];
}

// ---- pass B: one block per coarse bucket; count rows -> scan -> rowptr -> exact CSR place.
//      rowptr = cbase[b] + local prefix (cross-bucket carry already known). Scatter writes
//      confined to the bucket's ~130KB window -> L2-absorbed, flushed dense.
__global__ __launch_bounds__(1024) void csr_direct(
    const int2* __restrict__ stg1, const int* __restrict__ cbase,
    int* __restrict__ rowptr, int2* __restrict__ ecv, int N)
{
    __shared__ int cnt[RPB];      // 8 KB: counts, then reused as running fronts
    __shared__ int psum[1024];
    int b = blockIdx.x, t = threadIdx.x;
    int row0 = b << CSHIFT;
    int nrows = N - row0; if (nrows > RPB) nrows = RPB;
    int s = cbase[b], e = cbase[b + 1];
    cnt[t] = 0; cnt[t + 1024] = 0;
    __syncthreads();
    // pass 1: count local rows (contiguous L2/L3-resident reads)
    for (int i = s + t; i < e; i += 1024)
        atomicAdd(&cnt[(unsigned)stg1[i].x >> 19], 1);
    __syncthreads();
    // scan 2048 counters: 2 per thread + Hillis-Steele over 1024 partials
    int r0 = 2 * t, r1 = 2 * t + 1;
    int c0 = cnt[r0], c1 = cnt[r1];
    psum[t] = c0 + c1;
    __syncthreads();
    for (int off = 1; off < 1024; off <<= 1) {
        int x = (t >= off) ? psum[t - off] : 0;
        __syncthreads();
        psum[t] += x;
        __syncthreads();
    }
    int excl = psum[t] - c0 - c1;
    if (r0 < nrows) rowptr[row0 + r0] = s + excl;
    if (r1 < nrows) rowptr[row0 + r1] = s + excl + c0;
    if (t == 0 && row0 + nrows == N) rowptr[N] = e;
    __syncthreads();              // all cnt[] reads complete before overwrite
    cnt[r0] = excl;
    cnt[r1] = excl + c0;
    __syncthreads();
    // pass 2: place at exact CSR position (strip row bits, keep col|val)
    for (int i = s + t; i < e; i += 1024) {
        int2 cv = stg1[i];
        unsigned p = (unsigned)cv.x;
        int l = atomicAdd(&cnt[p >> 19], 1);
        ecv[s + l] = make_int2((int)(p & 0x7FFFFu), cv.y);
    }
}

// H[n,:] = act(in[n,:]) @ W[0:32,:] + b (stride HS) ; Z[n,:] = act(in[n,:]) @ W[32:64,:] (fp16, stride ZS)
template<int COUT, bool LRELU, int HS, int ZS>
__global__ __launch_bounds__(256) void dense_kernel(
    const float* in, const float* __restrict__ W,
    const float* __restrict__ b, float* H,
    half_t* __restrict__ Z, int N)
{
    int n = blockIdx.x * 256 + threadIdx.x;
    if (n >= N) return;
    const float* row = in + (size_t)n * 32;
    float xv[32];
#pragma unroll
    for (int f = 0; f < 32; f += 4) {
        float4 v = *(const float4*)(row + f);
        xv[f] = v.x; xv[f + 1] = v.y; xv[f + 2] = v.z; xv[f + 3] = v.w;
    }
    if (LRELU) {
#pragma unroll
        for (int f = 0; f < 32; f++) xv[f] = xv[f] > 0.f ? xv[f] : NEG_SLOPE * xv[f];
    }
    float acct[COUT], accb[COUT];
#pragma unroll
    for (int c = 0; c < COUT; c++) { acct[c] = b[c]; accb[c] = 0.f; }
#pragma unroll 4
    for (int f = 0; f < 32; f++) {
        float xf = xv[f];
#pragma unroll
        for (int c = 0; c < COUT; c++) {
            acct[c] = fmaf(xf, W[f * COUT + c], acct[c]);
            accb[c] = fmaf(xf, W[(32 + f) * COUT + c], accb[c]);
        }
    }
    float* hrow = H + (size_t)n * HS;
    half_t* zrow = Z + (size_t)n * ZS;
#pragma unroll
    for (int c = 0; c < COUT; c += 2)
        *(float2*)(hrow + c) = make_float2(acct[c], acct[c + 1]);
#pragma unroll
    for (int c = 0; c < COUT; c += 2) {
        half2_t h;
        h.x = (half_t)accb[c];
        h.y = (half_t)accb[c + 1];
        *(half2_t*)(zrow + c) = h;
    }
}

// CSR gather, 2 interleaved row-chains per thread (C=32, 8 lanes x half4) — 20 VGPR form
__global__ __launch_bounds__(256) void gather32(
    const int* __restrict__ rowptr, const int2* __restrict__ ecv,
    const half_t* __restrict__ Z, float* __restrict__ H, int N)
{
    int tid = blockIdx.x * 256 + threadIdx.x;
    int pr = tid >> 3, lane = tid & 7;
    int r0 = pr * 2, r1 = r0 + 1;
    if (r0 >= N) return;
    int s0 = rowptr[r0], e0 = rowptr[r0 + 1];
    int s1 = 0, e1 = 0;
    if (r1 < N) { s1 = rowptr[r1]; e1 = rowptr[r1 + 1]; }
    float ax0 = 0.f, ay0 = 0.f, az0 = 0.f, aw0 = 0.f;
    float ax1 = 0.f, ay1 = 0.f, az1 = 0.f, aw1 = 0.f;
    int i0 = s0, i1 = s1;
    while (i0 < e0 && i1 < e1) {
        int2 c0 = ecv[i0]; int2 c1 = ecv[i1];
        half4_t z0 = *(const half4_t*)(Z + (size_t)c0.x * 32 + lane * 4);
        half4_t z1 = *(const half4_t*)(Z + (size_t)c1.x * 32 + lane * 4);
        float v0 = __int_as_float(c0.y), v1 = __int_as_float(c1.y);
        ax0 = fmaf(v0, (float)z0.x, ax0); ay0 = fmaf(v0, (float)z0.y, ay0);
        az0 = fmaf(v0, (float)z0.z, az0); aw0 = fmaf(v0, (float)z0.w, aw0);
        ax1 = fmaf(v1, (float)z1.x, ax1); ay1 = fmaf(v1, (float)z1.y, ay1);
        az1 = fmaf(v1, (float)z1.z, az1); aw1 = fmaf(v1, (float)z1.w, aw1);
        i0++; i1++;
    }
    for (; i0 < e0; i0++) {
        int2 c0 = ecv[i0];
        half4_t z0 = *(const half4_t*)(Z + (size_t)c0.x * 32 + lane * 4);
        float v0 = __int_as_float(c0.y);
        ax0 = fmaf(v0, (float)z0.x, ax0); ay0 = fmaf(v0, (float)z0.y, ay0);
        az0 = fmaf(v0, (float)z0.z, az0); aw0 = fmaf(v0, (float)z0.w, aw0);
    }
    for (; i1 < e1; i1++) {
        int2 c1 = ecv[i1];
        half4_t z1 = *(const half4_t*)(Z + (size_t)c1.x * 32 + lane * 4);
        float v1 = __int_as_float(c1.y);
        ax1 = fmaf(v1, (float)z1.x, ax1); ay1 = fmaf(v1, (float)z1.y, ay1);
        az1 = fmaf(v1, (float)z1.z, az1); aw1 = fmaf(v1, (float)z1.w, aw1);
    }
    float4* hp0 = (float4*)(H + (size_t)r0 * 32 + lane * 4);
    float4 h0 = *hp0;
    h0.x += ax0; h0.y += ay0; h0.z += az0; h0.w += aw0;
    *hp0 = h0;
    if (r1 < N) {
        float4* hp1 = (float4*)(H + (size_t)r1 * 32 + lane * 4);
        float4 h1 = *hp1;
        h1.x += ax1; h1.y += ay1; h1.z += az1; h1.w += aw1;
        *hp1 = h1;
    }
}

// C=10 final gather: Z packed stride 16 halfs, H packed stride 16 floats, RMW (no atomics)
__global__ __launch_bounds__(256) void gather10(
    const int* __restrict__ rowptr, const int2* __restrict__ ecv,
    const half_t* __restrict__ Z, float* __restrict__ H, int N)
{
    int tid = blockIdx.x * 256 + threadIdx.x;
    int pr = tid >> 3, lane = tid & 7;
    int r0 = pr * 2, r1 = r0 + 1;
    if (r0 >= N || lane >= 5) return;
    int s0 = rowptr[r0], e0 = rowptr[r0 + 1];
    int s1 = 0, e1 = 0;
    if (r1 < N) { s1 = rowptr[r1]; e1 = rowptr[r1 + 1]; }
    float ax0 = 0.f, ay0 = 0.f, ax1 = 0.f, ay1 = 0.f;
    int i0 = s0, i1 = s1;
    while (i0 < e0 && i1 < e1) {
        int2 c0 = ecv[i0]; int2 c1 = ecv[i1];
        half2_t z0 = *(const half2_t*)(Z + (size_t)c0.x * 16 + lane * 2);
        half2_t z1 = *(const half2_t*)(Z + (size_t)c1.x * 16 + lane * 2);
        float v0 = __int_as_float(c0.y), v1 = __int_as_float(c1.y);
        ax0 = fmaf(v0, (float)z0.x, ax0); ay0 = fmaf(v0, (float)z0.y, ay0);
        ax1 = fmaf(v1, (float)z1.x, ax1); ay1 = fmaf(v1, (float)z1.y, ay1);
        i0++; i1++;
    }
    for (; i0 < e0; i0++) {
        int2 c0 = ecv[i0];
        half2_t z0 = *(const half2_t*)(Z + (size_t)c0.x * 16 + lane * 2);
        float v0 = __int_as_float(c0.y);
        ax0 = fmaf(v0, (float)z0.x, ax0); ay0 = fmaf(v0, (float)z0.y, ay0);
    }
    for (; i1 < e1; i1++) {
        int2 c1 = ecv[i1];
        half2_t z1 = *(const half2_t*)(Z + (size_t)c1.x * 16 + lane * 2);
        float v1 = __int_as_float(c1.y);
        ax1 = fmaf(v1, (float)z1.x, ax1); ay1 = fmaf(v1, (float)z1.y, ay1);
    }
    float* hp0 = H + (size_t)r0 * 16 + lane * 2;
    hp0[0] += ax0; hp0[1] += ay0;
    if (r1 < N) {
        float* hp1 = H + (size_t)r1 * 16 + lane * 2;
        hp1[0] += ax1; hp1[1] += ay1;
    }
}

// one block per graph; batch is sorted -> binary search node range, no atomics; H stride 16
__global__ __launch_bounds__(256) void pool_graph(
    const float* __restrict__ H, const int* __restrict__ batch,
    float* __restrict__ pool, int N, int dimoff)
{
    int g = blockIdx.x;
    int lo = 0, hi = N;
    while (lo < hi) { int mid = (lo + hi) >> 1; if (batch[mid] < g) lo = mid + 1; else hi = mid; }
    int start = lo;
    lo = start; hi = N;
    while (lo < hi) { int mid = (lo + hi) >> 1; if (batch[mid] < g + 1) lo = mid + 1; else hi = mid; }
    int end = lo;
    int t = threadIdx.x, f = t & 15, chain = t >> 4;
    __shared__ float sd[256];
    float acc = 0.f;
    if (f < 10) {
        for (int i = start + chain; i < end; i += 16) acc += H[(size_t)i * 16 + f];
    }
    sd[t] = acc; __syncthreads();
    if (chain == 0 && f < 10) {
        float s = 0.f;
#pragma unroll
        for (int k = 0; k < 16; k++) s += sd[k * 16 + f];
        int c = end - start;
        float inv = 1.f / (float)(c > 1 ? c : 1);
        pool[(size_t)g * 30 + dimoff + f] = s * inv;
    }
}

__global__ __launch_bounds__(256) void final_kernel(
    const float* __restrict__ pool, const float* __restrict__ Wf,
    const float* __restrict__ bfv, float* __restrict__ out, int G)
{
    int g = blockIdx.x * 256 + threadIdx.x;
    if (g >= G) return;
    float m[30];
#pragma unroll
    for (int j = 0; j < 30; j++) m[j] = pool[(size_t)g * 30 + j];
    float lg[10];
#pragma unroll
    for (int o = 0; o < 10; o++) {
        float a = bfv[o];
#pragma unroll
        for (int j = 0; j < 30; j++) a = fmaf(m[j], Wf[j * 10 + o], a);
        lg[o] = a;
    }
    float mx = lg[0];
#pragma unroll
    for (int o = 1; o < 10; o++) mx = fmaxf(mx, lg[o]);
    float s = 0.f;
#pragma unroll
    for (int o = 0; o < 10; o++) { lg[o] = __expf(lg[o] - mx); s += lg[o]; }
    float invs = 1.f / s;
#pragma unroll
    for (int o = 0; o < 10; o++) out[(size_t)g * 10 + o] = lg[o] * invs;
}

extern "C" void kernel_launch(void* const* d_in, const int* in_sizes, int n_in,
                              void* d_out, int out_size, void* d_ws, size_t ws_size,
                              hipStream_t stream)
{
    (void)n_in; (void)ws_size;
    const float* x[3]    = {(const float*)d_in[0], (const float*)d_in[1], (const float*)d_in[2]};
    const float* vals[3] = {(const float*)d_in[3], (const float*)d_in[4], (const float*)d_in[5]};
    const int* rows[3]   = {(const int*)d_in[6], (const int*)d_in[8], (const int*)d_in[10]};
    const int* cols[3]   = {(const int*)d_in[7], (const int*)d_in[9], (const int*)d_in[11]};
    const int* batch[3]  = {(const int*)d_in[12], (const int*)d_in[13], (const int*)d_in[14]};
    const float* W1[3] = {(const float*)d_in[16], (const float*)d_in[22], (const float*)d_in[28]};
    const float* b1[3] = {(const float*)d_in[17], (const float*)d_in[23], (const float*)d_in[29]};
    const float* W2[3] = {(const float*)d_in[18], (const float*)d_in[24], (const float*)d_in[30]};
    const float* b2[3] = {(const float*)d_in[19], (const float*)d_in[25], (const float*)d_in[31]};
    const float* W3[3] = {(const float*)d_in[20], (const float*)d_in[26], (const float*)d_in[32]};
    const float* b3[3] = {(const float*)d_in[21], (const float*)d_in[27], (const float*)d_in[33]};
    const float* Wf  = (const float*)d_in[34];
    const float* bfv = (const float*)d_in[35];
    float* out = (float*)d_out;

    int N[3] = {in_sizes[0] / 32, in_sizes[1] / 32, in_sizes[2] / 32};
    int E[3] = {in_sizes[3], in_sizes[4], in_sizes[5]};
    int G = out_size / 10;
    int maxN = N[0]; if (N[1] > maxN) maxN = N[1]; if (N[2] > maxN) maxN = N[2];
    int maxE = E[0]; if (E[1] > maxE) maxE = E[1]; if (E[2] > maxE) maxE = E[2];

    float* bufA   = (float*)d_ws;                       // layers; aliases stg1 during build
    float* bufZ   = bufA + (size_t)maxN * 32;           // Z1/Z2 (stride-32 halfs) then H3p+Z3p
    int2*  stg1   = (int2*)bufA;                        // build-phase only (maxE*8B <= maxN*128B)
    half_t* Zh    = (half_t*)bufZ;                      // fp16 Z view, stride 32 halfs (layers 1-2)
    float* H3p    = bufZ;                               // packed Htop3/Hfin3, stride 16 floats (after Z2 dead)
    half_t* Z3p   = (half_t*)(bufZ + (size_t)maxN * 16);// packed Z3, stride 16 halfs
    float* pool   = bufZ + (size_t)maxN * 32;
    int2*  ecv    = (int2*)(pool + (size_t)G * 30 + 2); // +2 for int2 alignment
    int*   rowptr = (int*)(ecv + maxE);
    int*   ccnt   = rowptr + (maxN + 1);
    int*   cbase  = ccnt + 256;
    int*   cfront = cbase + 258;

    for (int d = 0; d < 3; d++) {
        int n = N[d], e = E[d];
        int NBc = cdiv(n, RPB);
        int ntile = cdiv(e, TILE_E);
        int gsz = cdiv((long long)cdiv(n, 2) * 8, 256);

        // --- 2-level build: coarse split -> per-bucket direct CSR (count+scan+place) ---
        zero_i32<<<1, 256, 0, stream>>>(ccnt, 256);
        hist_coarse<<<ntile, 256, 0, stream>>>(rows[d], ccnt, e);
        scan_coarse<<<1, 64, 0, stream>>>(ccnt, cbase, cfront, NBc, e);
        split_coarse<<<ntile, 256, 0, stream>>>(rows[d], cols[d], vals[d], cfront, stg1, e);
        csr_direct<<<NBc, 1024, 0, stream>>>(stg1, cbase, rowptr, ecv, n);

        // --- 3 layers; pure gathers (low VGPR, high occupancy); streaming pool (no atomics) ---
        dense_kernel<32, false, 32, 32><<<cdiv(n, 256), 256, 0, stream>>>(x[d], W1[d], b1[d], bufA, Zh, n);
        gather32<<<gsz, 256, 0, stream>>>(rowptr, ecv, Zh, bufA, n);
        dense_kernel<32, true, 32, 32><<<cdiv(n, 256), 256, 0, stream>>>(bufA, W2[d], b2[d], bufA, Zh, n);
        gather32<<<gsz, 256, 0, stream>>>(rowptr, ecv, Zh, bufA, n);
        dense_kernel<10, true, 16, 16><<<cdiv(n, 256), 256, 0, stream>>>(bufA, W3[d], b3[d], H3p, Z3p, n);
        gather10<<<gsz, 256, 0, stream>>>(rowptr, ecv, Z3p, H3p, n);
        pool_graph<<<G, 256, 0, stream>>>(H3p, batch[d], pool, n, d * 10);
    }
    final_kernel<<<cdiv(G, 256), 256, 0, stream>>>(pool, Wf, bfv, out, G);
}

// Round 7
// 1362.634 us; speedup vs baseline: 1.1348x; 1.1348x over previous
//
#include <hip/hip_runtime.h>
#include <stdint.h>

#define NEG_SLOPE 0.01f
#define CSHIFT 13               // 8192 rows per coarse bucket
#define RALIGN (1 << CSHIFT)
#define MSHIFT 7                // 128 rows per mid bucket
#define MPC (1 << (CSHIFT - MSHIFT))   // 64 mids per coarse
#define MWIN 192                // window of mid-counters per split tile (straddle<=2 coarse)
#define CAP 4096                // max edges per mid bucket in csr_sort LDS
#define TILE_E 2048             // edges per split tile

typedef _Float16 half_t;
typedef _Float16 half2_t __attribute__((ext_vector_type(2)));
typedef _Float16 half4_t __attribute__((ext_vector_type(4)));

static inline int cdiv(long long a, long long b) { return (int)((a + b - 1) / b); }

// up to 3 edge sources concatenated: [0,e1) dim0 (+0), [e1,e2) dim1 (+o1), [e2,etot) dim2 (+o2)
struct Src3 {
    const int* r0; const int* c0; const float* v0;
    const int* r1; const int* c1; const float* v1;
    const int* r2; const int* c2; const float* v2;
    int e1, e2, etot;
    int o1, o2;
};

__device__ __forceinline__ int fetch_row(const Src3& S, int e) {
    if (e < S.e1) return S.r0[e];
    if (e < S.e2) return S.r1[e - S.e1] + S.o1;
    return S.r2[e - S.e2] + S.o2;
}
__device__ __forceinline__ void fetch_edge(const Src3& S, int e, int& r, unsigned& c, float& v) {
    if (e < S.e1) { r = S.r0[e]; c = (unsigned)S.c0[e]; v = S.v0[e]; }
    else if (e < S.e2) { int i = e - S.e1; r = S.r1[i] + S.o1; c = (unsigned)S.c1[i]; v = S.v1[i]; }
    else { int i = e - S.e2; r = S.r2[i] + S.o2; c = (unsigned)S.c2[i]; v = S.v2[i]; }
}

__global__ __launch_bounds__(256) void zero_i32(int* __restrict__ p, int n) {
    int i = blockIdx.x * 256 + threadIdx.x;
    if (i < n) p[i] = 0;
}

// ---- coarse histogram: LDS counters (<=256 buckets), one merge atomic per (block,bucket) ----
__global__ __launch_bounds__(256) void hist_coarse(Src3 S, int* __restrict__ ccnt) {
    __shared__ int cnt[256];
    int t = threadIdx.x;
    cnt[t] = 0;
    __syncthreads();
    int base = blockIdx.x * TILE_E;
#pragma unroll
    for (int k = 0; k < TILE_E / 256; k++) {
        int e = base + k * 256 + t;
        if (e < S.etot) atomicAdd(&cnt[fetch_row(S, e) >> CSHIFT], 1);
    }
    __syncthreads();
    if (cnt[t] > 0) atomicAdd(&ccnt[t], cnt[t]);
}

__global__ void scan_coarse(const int* __restrict__ ccnt, int* __restrict__ cbase,
                            int* __restrict__ cfront, int NBc, int E) {
    if (threadIdx.x == 0 && blockIdx.x == 0) {
        int run = 0;
        for (int b = 0; b < NBc; b++) { cbase[b] = run; cfront[b] = run; run += ccnt[b]; }
        cbase[NBc] = E;
    }
}

// ---- pass A: LDS multisplit into coarse buckets; dense chunk writes ----
// record: ( (row & 8191) << 19 | col_local , val )   [13+19 = 32 bits, col_local < 2^19]
__global__ __launch_bounds__(256) void split_coarse(
    Src3 S, int* __restrict__ cfront, int2* __restrict__ stg1)
{
    __shared__ int cnt[256], gb[256];
    int t = threadIdx.x;
    cnt[t] = 0;
    __syncthreads();
    int base = blockIdx.x * TILE_E;
    int myb[8], myrank[8]; int2 mycv[8];
#pragma unroll
    for (int k = 0; k < 8; k++) {
        int e = base + k * 256 + t;
        myb[k] = -1;
        if (e < S.etot) {
            int r; unsigned c; float v;
            fetch_edge(S, e, r, c, v);
            int b = r >> CSHIFT;
            mycv[k] = make_int2((int)(((unsigned)(r & (RALIGN - 1)) << 19) | c),
                                __float_as_int(v));
            myb[k] = b;
            myrank[k] = atomicAdd(&cnt[b], 1);
        }
    }
    __syncthreads();
    if (cnt[t] > 0) gb[t] = atomicAdd(&cfront[t], cnt[t]);
    __syncthreads();
#pragma unroll
    for (int k = 0; k < 8; k++)
        if (myb[k] >= 0) stg1[gb[myb[k]] + myrank[k]] = mycv[k];
}

// ---- mid histogram from coarse-sorted staging (windowed LDS counters) ----
__global__ __launch_bounds__(256) void hist_mid(
    const int2* __restrict__ stg1, const int* __restrict__ cbase_g,
    int* __restrict__ mcnt, int E, int NBc)
{
    __shared__ int cb[258];
    __shared__ int wc[MWIN];
    int t = threadIdx.x;
    for (int i = t; i <= NBc; i += 256) cb[i] = cbase_g[i];
    for (int i = t; i < MWIN; i += 256) wc[i] = 0;
    __syncthreads();
    int base = blockIdx.x * TILE_E;
    int lo = 0, hi = NBc - 1;
    while (lo < hi) { int m = (lo + hi + 1) >> 1; if (cb[m] <= base) lo = m; else hi = m - 1; }
    int winm = lo * MPC;
#pragma unroll
    for (int k = 0; k < 8; k++) {
        int e = base + k * 256 + t;
        if (e < E) {
            int b = lo;
            while (cb[b + 1] <= e) b++;
            int m = b * MPC + (int)(((unsigned)stg1[e].x >> 19) >> MSHIFT);
            int lf = m - winm;
            if (lf >= 0 && lf < MWIN) atomicAdd(&wc[lf], 1);
            else atomicAdd(&mcnt[m], 1);    // rare fallback
        }
    }
    __syncthreads();
    for (int i = t; i < MWIN; i += 256)
        if (wc[i] > 0) atomicAdd(&mcnt[winm + i], wc[i]);
}

// ---- single-block scan over mid buckets -> mbase, mfront ----
__global__ __launch_bounds__(256) void scan_mid(
    const int* __restrict__ mcnt, int* __restrict__ mbase,
    int* __restrict__ mfront, int NBm, int E)
{
    __shared__ int sd[256];
    __shared__ int carry;
    int t = threadIdx.x;
    if (t == 0) carry = 0;
    __syncthreads();
    for (int base = 0; base < NBm; base += 256) {
        int v = (base + t < NBm) ? mcnt[base + t] : 0;
        sd[t] = v;
        __syncthreads();
        for (int off = 1; off < 256; off <<= 1) {
            int x = (t >= off) ? sd[t - off] : 0;
            __syncthreads();
            sd[t] += x;
            __syncthreads();
        }
        int incl = sd[t] + carry;
        int excl = incl - v;
        if (base + t < NBm) { mbase[base + t] = excl; mfront[base + t] = excl; }
        __syncthreads();
        if (t == 255) carry = incl;
        __syncthreads();
    }
    if (t == 0) mbase[NBm] = E;
}

// ---- pass B: coarse-sorted staging -> mid (128-row) buckets; windowed LDS ranking ----
__global__ __launch_bounds__(256) void split_mid(
    const int2* __restrict__ stg1, const int* __restrict__ cbase_g,
    int* __restrict__ mfront, int2* __restrict__ stgm, int E, int NBc)
{
    __shared__ int cb[258];
    __shared__ int wc[MWIN], wg[MWIN];
    int t = threadIdx.x;
    for (int i = t; i <= NBc; i += 256) cb[i] = cbase_g[i];
    for (int i = t; i < MWIN; i += 256) wc[i] = 0;
    __syncthreads();
    int base = blockIdx.x * TILE_E;
    int lo = 0, hi = NBc - 1;
    while (lo < hi) { int m = (lo + hi + 1) >> 1; if (cb[m] <= base) lo = m; else hi = m - 1; }
    int winm = lo * MPC;
    int mylf[8], myrank[8]; int2 myp[8];
#pragma unroll
    for (int k = 0; k < 8; k++) {
        int e = base + k * 256 + t;
        mylf[k] = -1;
        if (e < E) {
            int b = lo;
            while (cb[b + 1] <= e) b++;
            int2 cv = stg1[e];
            int m = (b << (CSHIFT - MSHIFT)) + (int)(((unsigned)cv.x >> 19) >> MSHIFT);
            int lf = m - winm;
            if (lf >= 0 && lf < MWIN) { mylf[k] = lf; myrank[k] = atomicAdd(&wc[lf], 1); myp[k] = cv; }
            else stgm[atomicAdd(&mfront[m], 1)] = cv;   // rare fallback
        }
    }
    __syncthreads();
    for (int i = t; i < MWIN; i += 256)
        if (wc[i] > 0) wg[i] = atomicAdd(&mfront[winm + i], wc[i]);
    __syncthreads();
#pragma unroll
    for (int k = 0; k < 8; k++)
        if (mylf[k] >= 0) stgm[wg[mylf[k]] + myrank[k]] = myp[k];
}

// ---- pass C: one block per mid bucket; LDS counting sort to exact CSR ----
__global__ __launch_bounds__(256) void csr_sort(
    const int2* __restrict__ stgm, const int* __restrict__ mbase,
    int* __restrict__ rowptr, int2* __restrict__ ecv, int N)
{
    __shared__ int2 buf[CAP];
    __shared__ int cnt[128], sc[128], front[128];
    int mb = blockIdx.x, t = threadIdx.x;
    int row0 = mb << MSHIFT;
    int nrows = N - row0; if (nrows > 128) nrows = 128;
    int s = mbase[mb], eend = mbase[mb + 1];
    if (t < 128) cnt[t] = 0;
    __syncthreads();
    for (int i = s + t; i < eend; i += 256)
        atomicAdd(&cnt[((unsigned)stgm[i].x >> 19) & 127], 1);
    __syncthreads();
    if (t < 128) sc[t] = cnt[t];
    __syncthreads();
    for (int off = 1; off < 128; off <<= 1) {
        int x = (t >= off && t < 128) ? sc[t - off] : 0;
        __syncthreads();
        if (t < 128) sc[t] += x;
        __syncthreads();
    }
    if (t < 128) front[t] = sc[t] - cnt[t];
    if (t < nrows) rowptr[row0 + t] = s + sc[t] - cnt[t];
    if (t == 0 && row0 + nrows == N) rowptr[N] = eend;
    __syncthreads();
    for (int i = s + t; i < eend; i += 256) {
        int2 cv = stgm[i];
        unsigned p = (unsigned)cv.x;
        int rl = ((int)(p >> 19)) & 127;
        int2 rec = make_int2((int)(p & 0x7FFFFu), cv.y);
        int l = atomicAdd(&front[rl], 1);
        if (l < CAP) buf[l] = rec;
        else ecv[s + l] = rec;               // overflow fallback (statistically never)
    }
    __syncthreads();
    int total = eend - s; if (total > CAP) total = CAP;
    for (int l = t; l < total; l += 256) ecv[s + l] = buf[l];
}

// H[n,:] = act(in[n,:]) @ W[0:32,:] + b (stride HS) ; Z[n,:] = act(in[n,:]) @ W[32:64,:] (fp16, stride ZS)
template<int COUT, bool LRELU, int HS, int ZS>
__global__ __launch_bounds__(256) void dense_kernel(
    const float* in, const float* __restrict__ W,
    const float* __restrict__ b, float* H,
    half_t* __restrict__ Z, int N)
{
    int n = blockIdx.x * 256 + threadIdx.x;
    if (n >= N) return;
    const float* row = in + (size_t)n * 32;
    float xv[32];
#pragma unroll
    for (int f = 0; f < 32; f += 4) {
        float4 v = *(const float4*)(row + f);
        xv[f] = v.x; xv[f + 1] = v.y; xv[f + 2] = v.z; xv[f + 3] = v.w;
    }
    if (LRELU) {
#pragma unroll
        for (int f = 0; f < 32; f++) xv[f] = xv[f] > 0.f ? xv[f] : NEG_SLOPE * xv[f];
    }
    float acct[COUT], accb[COUT];
#pragma unroll
    for (int c = 0; c < COUT; c++) { acct[c] = b[c]; accb[c] = 0.f; }
#pragma unroll 4
    for (int f = 0; f < 32; f++) {
        float xf = xv[f];
#pragma unroll
        for (int c = 0; c < COUT; c++) {
            acct[c] = fmaf(xf, W[f * COUT + c], acct[c]);
            accb[c] = fmaf(xf, W[(32 + f) * COUT + c], accb[c]);
        }
    }
    float* hrow = H + (size_t)n * HS;
    half_t* zrow = Z + (size_t)n * ZS;
#pragma unroll
    for (int c = 0; c < COUT; c += 2)
        *(float2*)(hrow + c) = make_float2(acct[c], acct[c + 1]);
#pragma unroll
    for (int c = 0; c < COUT; c += 2) {
        half2_t h;
        h.x = (half_t)accb[c];
        h.y = (half_t)accb[c + 1];
        *(half2_t*)(zrow + c) = h;
    }
}

// CSR gather, 2 interleaved row-chains per thread (C=32, 8 lanes x half4) — 20 VGPR form
__global__ __launch_bounds__(256) void gather32(
    const int* __restrict__ rowptr, const int2* __restrict__ ecv,
    const half_t* __restrict__ Z, float* __restrict__ H, int N)
{
    int tid = blockIdx.x * 256 + threadIdx.x;
    int pr = tid >> 3, lane = tid & 7;
    int r0 = pr * 2, r1 = r0 + 1;
    if (r0 >= N) return;
    int s0 = rowptr[r0], e0 = rowptr[r0 + 1];
    int s1 = 0, e1 = 0;
    if (r1 < N) { s1 = rowptr[r1]; e1 = rowptr[r1 + 1]; }
    float ax0 = 0.f, ay0 = 0.f, az0 = 0.f, aw0 = 0.f;
    float ax1 = 0.f, ay1 = 0.f, az1 = 0.f, aw1 = 0.f;
    int i0 = s0, i1 = s1;
    while (i0 < e0 && i1 < e1) {
        int2 c0 = ecv[i0]; int2 c1 = ecv[i1];
        half4_t z0 = *(const half4_t*)(Z + (size_t)c0.x * 32 + lane * 4);
        half4_t z1 = *(const half4_t*)(Z + (size_t)c1.x * 32 + lane * 4);
        float v0 = __int_as_float(c0.y), v1 = __int_as_float(c1.y);
        ax0 = fmaf(v0, (float)z0.x, ax0); ay0 = fmaf(v0, (float)z0.y, ay0);
        az0 = fmaf(v0, (float)z0.z, az0); aw0 = fmaf(v0, (float)z0.w, aw0);
        ax1 = fmaf(v1, (float)z1.x, ax1); ay1 = fmaf(v1, (float)z1.y, ay1);
        az1 = fmaf(v1, (float)z1.z, az1); aw1 = fmaf(v1, (float)z1.w, aw1);
        i0++; i1++;
    }
    for (; i0 < e0; i0++) {
        int2 c0 = ecv[i0];
        half4_t z0 = *(const half4_t*)(Z + (size_t)c0.x * 32 + lane * 4);
        float v0 = __int_as_float(c0.y);
        ax0 = fmaf(v0, (float)z0.x, ax0); ay0 = fmaf(v0, (float)z0.y, ay0);
        az0 = fmaf(v0, (float)z0.z, az0); aw0 = fmaf(v0, (float)z0.w, aw0);
    }
    for (; i1 < e1; i1++) {
        int2 c1 = ecv[i1];
        half4_t z1 = *(const half4_t*)(Z + (size_t)c1.x * 32 + lane * 4);
        float v1 = __int_as_float(c1.y);
        ax1 = fmaf(v1, (float)z1.x, ax1); ay1 = fmaf(v1, (float)z1.y, ay1);
        az1 = fmaf(v1, (float)z1.z, az1); aw1 = fmaf(v1, (float)z1.w, aw1);
    }
    float4* hp0 = (float4*)(H + (size_t)r0 * 32 + lane * 4);
    float4 h0 = *hp0;
    h0.x += ax0; h0.y += ay0; h0.z += az0; h0.w += aw0;
    *hp0 = h0;
    if (r1 < N) {
        float4* hp1 = (float4*)(H + (size_t)r1 * 32 + lane * 4);
        float4 h1 = *hp1;
        h1.x += ax1; h1.y += ay1; h1.z += az1; h1.w += aw1;
        *hp1 = h1;
    }
}

// C=10 final gather: Z packed stride 16 halfs, H packed stride 16 floats, RMW (no atomics)
__global__ __launch_bounds__(256) void gather10(
    const int* __restrict__ rowptr, const int2* __restrict__ ecv,
    const half_t* __restrict__ Z, float* __restrict__ H, int N)
{
    int tid = blockIdx.x * 256 + threadIdx.x;
    int pr = tid >> 3, lane = tid & 7;
    int r0 = pr * 2, r1 = r0 + 1;
    if (r0 >= N || lane >= 5) return;
    int s0 = rowptr[r0], e0 = rowptr[r0 + 1];
    int s1 = 0, e1 = 0;
    if (r1 < N) { s1 = rowptr[r1]; e1 = rowptr[r1 + 1]; }
    float ax0 = 0.f, ay0 = 0.f, ax1 = 0.f, ay1 = 0.f;
    int i0 = s0, i1 = s1;
    while (i0 < e0 && i1 < e1) {
        int2 c0 = ecv[i0]; int2 c1 = ecv[i1];
        half2_t z0 = *(const half2_t*)(Z + (size_t)c0.x * 16 + lane * 2);
        half2_t z1 = *(const half2_t*)(Z + (size_t)c1.x * 16 + lane * 2);
        float v0 = __int_as_float(c0.y), v1 = __int_as_float(c1.y);
        ax0 = fmaf(v0, (float)z0.x, ax0); ay0 = fmaf(v0, (float)z0.y, ay0);
        ax1 = fmaf(v1, (float)z1.x, ax1); ay1 = fmaf(v1, (float)z1.y, ay1);
        i0++; i1++;
    }
    for (; i0 < e0; i0++) {
        int2 c0 = ecv[i0];
        half2_t z0 = *(const half2_t*)(Z + (size_t)c0.x * 16 + lane * 2);
        float v0 = __int_as_float(c0.y);
        ax0 = fmaf(v0, (float)z0.x, ax0); ay0 = fmaf(v0, (float)z0.y, ay0);
    }
    for (; i1 < e1; i1++) {
        int2 c1 = ecv[i1];
        half2_t z1 = *(const half2_t*)(Z + (size_t)c1.x * 16 + lane * 2);
        float v1 = __int_as_float(c1.y);
        ax1 = fmaf(v1, (float)z1.x, ax1); ay1 = fmaf(v1, (float)z1.y, ay1);
    }
    float* hp0 = H + (size_t)r0 * 16 + lane * 2;
    hp0[0] += ax0; hp0[1] += ay0;
    if (r1 < N) {
        float* hp1 = H + (size_t)r1 * 16 + lane * 2;
        hp1[0] += ax1; hp1[1] += ay1;
    }
}

// one block per graph; batch is sorted -> binary search node range, no atomics; H stride 16
__global__ __launch_bounds__(256) void pool_graph(
    const float* __restrict__ H, const int* __restrict__ batch,
    float* __restrict__ pool, int N, int dimoff)
{
    int g = blockIdx.x;
    int lo = 0, hi = N;
    while (lo < hi) { int mid = (lo + hi) >> 1; if (batch[mid] < g) lo = mid + 1; else hi = mid; }
    int start = lo;
    lo = start; hi = N;
    while (lo < hi) { int mid = (lo + hi) >> 1; if (batch[mid] < g + 1) lo = mid + 1; else hi = mid; }
    int end = lo;
    int t = threadIdx.x, f = t & 15, chain = t >> 4;
    __shared__ float sd[256];
    float acc = 0.f;
    if (f < 10) {
        for (int i = start + chain; i < end; i += 16) acc += H[(size_t)i * 16 + f];
    }
    sd[t] = acc; __syncthreads();
    if (chain == 0 && f < 10) {
        float s = 0.f;
#pragma unroll
        for (int k = 0; k < 16; k++) s += sd[k * 16 + f];
        int c = end - start;
        float inv = 1.f / (float)(c > 1 ? c : 1);
        pool[(size_t)g * 30 + dimoff + f] = s * inv;
    }
}

__global__ __launch_bounds__(256) void final_kernel(
    const float* __restrict__ pool, const float* __restrict__ Wf,
    const float* __restrict__ bfv, float* __restrict__ out, int G)
{
    int g = blockIdx.x * 256 + threadIdx.x;
    if (g >= G) return;
    float m[30];
#pragma unroll
    for (int j = 0; j < 30; j++) m[j] = pool[(size_t)g * 30 + j];
    float lg[10];
#pragma unroll
    for (int o = 0; o < 10; o++) {
        float a = bfv[o];
#pragma unroll
        for (int j = 0; j < 30; j++) a = fmaf(m[j], Wf[j * 10 + o], a);
        lg[o] = a;
    }
    float mx = lg[0];
#pragma unroll
    for (int o = 1; o < 10; o++) mx = fmaxf(mx, lg[o]);
    float s = 0.f;
#pragma unroll
    for (int o = 0; o < 10; o++) { lg[o] = __expf(lg[o] - mx); s += lg[o]; }
    float invs = 1.f / s;
#pragma unroll
    for (int o = 0; o < 10; o++) out[(size_t)g * 10 + o] = lg[o] * invs;
}

extern "C" void kernel_launch(void* const* d_in, const int* in_sizes, int n_in,
                              void* d_out, int out_size, void* d_ws, size_t ws_size,
                              hipStream_t stream)
{
    (void)n_in;
    const float* x[3]    = {(const float*)d_in[0], (const float*)d_in[1], (const float*)d_in[2]};
    const float* vals[3] = {(const float*)d_in[3], (const float*)d_in[4], (const float*)d_in[5]};
    const int* rows[3]   = {(const int*)d_in[6], (const int*)d_in[8], (const int*)d_in[10]};
    const int* cols[3]   = {(const int*)d_in[7], (const int*)d_in[9], (const int*)d_in[11]};
    const int* batch[3]  = {(const int*)d_in[12], (const int*)d_in[13], (const int*)d_in[14]};
    const float* W1[3] = {(const float*)d_in[16], (const float*)d_in[22], (const float*)d_in[28]};
    const float* b1[3] = {(const float*)d_in[17], (const float*)d_in[23], (const float*)d_in[29]};
    const float* W2[3] = {(const float*)d_in[18], (const float*)d_in[24], (const float*)d_in[30]};
    const float* b2[3] = {(const float*)d_in[19], (const float*)d_in[25], (const float*)d_in[31]};
    const float* W3[3] = {(const float*)d_in[20], (const float*)d_in[26], (const float*)d_in[32]};
    const float* b3[3] = {(const float*)d_in[21], (const float*)d_in[27], (const float*)d_in[33]};
    const float* Wf  = (const float*)d_in[34];
    const float* bfv = (const float*)d_in[35];
    float* out = (float*)d_out;

    int N[3] = {in_sizes[0] / 32, in_sizes[1] / 32, in_sizes[2] / 32};
    int E[3] = {in_sizes[3], in_sizes[4], in_sizes[5]};
    int G = out_size / 10;
    int maxN = N[0]; if (N[1] > maxN) maxN = N[1]; if (N[2] > maxN) maxN = N[2];
    int maxE = E[0]; if (E[1] > maxE) maxE = E[1]; if (E[2] > maxE) maxE = E[2];

    // union (bucket-aligned) row offsets; cols stay LOCAL everywhere
    int o1 = cdiv(N[0], RALIGN) * RALIGN;
    int o2 = o1 + cdiv(N[1], RALIGN) * RALIGN;
    int NU = o2 + N[2];
    long long EU = (long long)E[0] + E[1] + E[2];
    int NBcU = cdiv(NU, RALIGN);
    int NBmU = cdiv(NU, 1 << MSHIFT);

    // shared compute-phase layout (local per-dim buffers, sized by maxN) — identical to R5
    float* bufA = (float*)d_ws;                          // H (stride 32); aliases stg1 during build
    float* bufZ = bufA + (size_t)maxN * 32;              // Z1/Z2 stride-32 halfs; H3p+Z3p packed
    half_t* Zh  = (half_t*)bufZ;
    float* H3p  = bufZ;
    half_t* Z3p = (half_t*)(bufZ + (size_t)maxN * 16);
    float* pool = bufZ + (size_t)maxN * 32;
    int2* stg1  = (int2*)bufA;                           // build-phase only
    int2* ecv   = (int2*)(pool + (size_t)G * 30 + 2);

    // --- batched-build layout (union): [ecv EU][rowptr NU+1][mcnt|mbase|mfront][ccnt|cbase|cfront][stgm EU]
    int* rowptrU = (int*)(ecv + EU);
    int* mcntU   = rowptrU + (NU + 1);
    int* mbaseU  = mcntU + NBmU;
    int* mfrontU = mbaseU + (NBmU + 1);
    int* ccntU   = mfrontU + NBmU;
    int* cbaseU  = ccntU + 256;
    int* cfrontU = cbaseU + 258;
    uintptr_t sp = ((uintptr_t)(cfrontU + 256) + 7) & ~(uintptr_t)7;
    int2* stgmU  = (int2*)sp;
    size_t needU = (size_t)((char*)(stgmU + EU) - (char*)d_ws);
    bool batched = (needU <= ws_size) && (EU * 8 <= (size_t)maxN * 256);  // stg1 fits bufA+bufZ

    int offs[3] = {0, o1, o2};

    if (batched) {
        // ---- ONE union build for all 3 dims (8 launches instead of 27) ----
        Src3 S;
        S.r0 = rows[0]; S.c0 = cols[0]; S.v0 = vals[0];
        S.r1 = rows[1]; S.c1 = cols[1]; S.v1 = vals[1];
        S.r2 = rows[2]; S.c2 = cols[2]; S.v2 = vals[2];
        S.e1 = E[0]; S.e2 = E[0] + E[1]; S.etot = (int)EU;
        S.o1 = o1; S.o2 = o2;
        int ntileU = cdiv(EU, TILE_E);
        int zlenU = 3 * NBmU + 257;          // mcnt + mbase + mfront + ccnt (contiguous)
        zero_i32<<<cdiv(zlenU, 256), 256, 0, stream>>>(mcntU, zlenU);
        hist_coarse<<<ntileU, 256, 0, stream>>>(S, ccntU);
        scan_coarse<<<1, 64, 0, stream>>>(ccntU, cbaseU, cfrontU, NBcU, (int)EU);
        split_coarse<<<ntileU, 256, 0, stream>>>(S, cfrontU, stg1);
        hist_mid<<<ntileU, 256, 0, stream>>>(stg1, cbaseU, mcntU, (int)EU, NBcU);
        scan_mid<<<1, 256, 0, stream>>>(mcntU, mbaseU, mfrontU, NBmU, (int)EU);
        split_mid<<<ntileU, 256, 0, stream>>>(stg1, cbaseU, mfrontU, stgmU, (int)EU, NBcU);
        csr_sort<<<NBmU, 256, 0, stream>>>(stgmU, mbaseU, rowptrU, ecv, NU);

        // ---- per-dim compute (unchanged from R5; rowptr slice is union-offset) ----
        for (int d = 0; d < 3; d++) {
            int n = N[d];
            int gsz = cdiv((long long)cdiv(n, 2) * 8, 256);
            const int* rp = rowptrU + offs[d];
            dense_kernel<32, false, 32, 32><<<cdiv(n, 256), 256, 0, stream>>>(x[d], W1[d], b1[d], bufA, Zh, n);
            gather32<<<gsz, 256, 0, stream>>>(rp, ecv, Zh, bufA, n);
            dense_kernel<32, true, 32, 32><<<cdiv(n, 256), 256, 0, stream>>>(bufA, W2[d], b2[d], bufA, Zh, n);
            gather32<<<gsz, 256, 0, stream>>>(rp, ecv, Zh, bufA, n);
            dense_kernel<10, true, 16, 16><<<cdiv(n, 256), 256, 0, stream>>>(bufA, W3[d], b3[d], H3p, Z3p, n);
            gather10<<<gsz, 256, 0, stream>>>(rp, ecv, Z3p, H3p, n);
            pool_graph<<<G, 256, 0, stream>>>(H3p, batch[d], pool, n, d * 10);
        }
    } else {
        // ---- fallback: exact R5 per-dim 3-level build (proven 1423 us) ----
        int maxNBm = cdiv(maxN, 1 << MSHIFT);
        int* rowptr = (int*)(ecv + maxE);
        int* mcnt   = rowptr + (maxN + 1);
        int* mbase  = mcnt + maxNBm;
        int* mfront = mbase + (maxNBm + 1);
        int* ccnt   = mfront + maxNBm;
        int* cbase  = ccnt + 256;
        int* cfront = cbase + 258;
        int2* stgm  = (int2*)bufZ;
        int zlen = 3 * maxNBm + 257;
        for (int d = 0; d < 3; d++) {
            int n = N[d], e = E[d];
            int NBc = cdiv(n, RALIGN);
            int NBm = cdiv(n, 1 << MSHIFT);
            int ntile = cdiv(e, TILE_E);
            int gsz = cdiv((long long)cdiv(n, 2) * 8, 256);
            Src3 S;
            S.r0 = rows[d]; S.c0 = cols[d]; S.v0 = vals[d];
            S.r1 = rows[d]; S.c1 = cols[d]; S.v1 = vals[d];
            S.r2 = rows[d]; S.c2 = cols[d]; S.v2 = vals[d];
            S.e1 = e; S.e2 = e; S.etot = e; S.o1 = 0; S.o2 = 0;
            zero_i32<<<cdiv(zlen, 256), 256, 0, stream>>>(mcnt, zlen);
            hist_coarse<<<ntile, 256, 0, stream>>>(S, ccnt);
            scan_coarse<<<1, 64, 0, stream>>>(ccnt, cbase, cfront, NBc, e);
            split_coarse<<<ntile, 256, 0, stream>>>(S, cfront, stg1);
            hist_mid<<<ntile, 256, 0, stream>>>(stg1, cbase, mcnt, e, NBc);
            scan_mid<<<1, 256, 0, stream>>>(mcnt, mbase, mfront, NBm, e);
            split_mid<<<ntile, 256, 0, stream>>>(stg1, cbase, mfront, stgm, e, NBc);
            csr_sort<<<NBm, 256, 0, stream>>>(stgm, mbase, rowptr, ecv, n);
            dense_kernel<32, false, 32, 32><<<cdiv(n, 256), 256, 0, stream>>>(x[d], W1[d], b1[d], bufA, Zh, n);
            gather32<<<gsz, 256, 0, stream>>>(rowptr, ecv, Zh, bufA, n);
            dense_kernel<32, true, 32, 32><<<cdiv(n, 256), 256, 0, stream>>>(bufA, W2[d], b2[d], bufA, Zh, n);
            gather32<<<gsz, 256, 0, stream>>>(rowptr, ecv, Zh, bufA, n);
            dense_kernel<10, true, 16, 16><<<cdiv(n, 256), 256, 0, stream>>>(bufA, W3[d], b3[d], H3p, Z3p, n);
            gather10<<<gsz, 256, 0, stream>>>(rowptr, ecv, Z3p, H3p, n);
            pool_graph<<<G, 256, 0, stream>>>(H3p, batch[d], pool, n, d * 10);
        }
    }
    final_kernel<<<cdiv(G, 256), 256, 0, stream>>>(pool, Wf, bfv, out, G);
}

// Round 9
// 1181.392 us; speedup vs baseline: 1.3089x; 1.1534x over previous
//
#include <hip/hip_runtime.h>
#include <stdint.h>

#define NEG_SLOPE 0.01f
#define CSHIFT 13               // 8192 rows per coarse bucket
#define RALIGN (1 << CSHIFT)
#define MSHIFT 7                // 128 rows per mid bucket
#define MPC (1 << (CSHIFT - MSHIFT))   // 64 mids per coarse
#define MWIN 192                // window of mid-counters per split tile (straddle<=2 coarse)
#define CAP 4096                // max edges per mid bucket in csr_sort LDS
#define TILE_E 2048             // edges per split tile

typedef _Float16 half_t;
typedef _Float16 half2_t __attribute__((ext_vector_type(2)));
typedef _Float16 half4_t __attribute__((ext_vector_type(4)));

static inline int cdiv(long long a, long long b) { return (int)((a + b - 1) / b); }
static inline size_t al16(size_t x) { return (x + 15) & ~(size_t)15; }

// up to 3 edge sources concatenated: [0,e1) dim0 (+0), [e1,e2) dim1 (+o1), [e2,etot) dim2 (+o2)
struct Src3 {
    const int* r0; const int* c0; const float* v0;
    const int* r1; const int* c1; const float* v1;
    const int* r2; const int* c2; const float* v2;
    int e1, e2, etot;
    int o1, o2;
};

__device__ __forceinline__ int fetch_row(const Src3& S, int e) {
    if (e < S.e1) return S.r0[e];
    if (e < S.e2) return S.r1[e - S.e1] + S.o1;
    return S.r2[e - S.e2] + S.o2;
}
__device__ __forceinline__ void fetch_edge(const Src3& S, int e, int& r, unsigned& c, float& v) {
    if (e < S.e1) { r = S.r0[e]; c = (unsigned)S.c0[e]; v = S.v0[e]; }
    else if (e < S.e2) { int i = e - S.e1; r = S.r1[i] + S.o1; c = (unsigned)S.c1[i]; v = S.v1[i]; }
    else { int i = e - S.e2; r = S.r2[i] + S.o2; c = (unsigned)S.c2[i]; v = S.v2[i]; }
}

__global__ __launch_bounds__(256) void zero_i32(int* __restrict__ p, int n) {
    int i = blockIdx.x * 256 + threadIdx.x;
    if (i < n) p[i] = 0;
}

// ---- coarse histogram: LDS counters (<=256 buckets), one merge atomic per (block,bucket) ----
__global__ __launch_bounds__(256) void hist_coarse(Src3 S, int* __restrict__ ccnt) {
    __shared__ int cnt[256];
    int t = threadIdx.x;
    cnt[t] = 0;
    __syncthreads();
    int base = blockIdx.x * TILE_E;
#pragma unroll
    for (int k = 0; k < TILE_E / 256; k++) {
        int e = base + k * 256 + t;
        if (e < S.etot) atomicAdd(&cnt[fetch_row(S, e) >> CSHIFT], 1);
    }
    __syncthreads();
    if (cnt[t] > 0) atomicAdd(&ccnt[t], cnt[t]);
}

__global__ void scan_coarse(const int* __restrict__ ccnt, int* __restrict__ cbase,
                            int* __restrict__ cfront, int NBc, int E) {
    if (threadIdx.x == 0 && blockIdx.x == 0) {
        int run = 0;
        for (int b = 0; b < NBc; b++) { cbase[b] = run; cfront[b] = run; run += ccnt[b]; }
        cbase[NBc] = E;
    }
}

// ---- pass A: LDS multisplit into coarse buckets; dense chunk writes ----
// record: ( (row & 8191) << 19 | col_local , val )
__global__ __launch_bounds__(256) void split_coarse(
    Src3 S, int* __restrict__ cfront, int2* __restrict__ stg1)
{
    __shared__ int cnt[256], gb[256];
    int t = threadIdx.x;
    cnt[t] = 0;
    __syncthreads();
    int base = blockIdx.x * TILE_E;
    int myb[8], myrank[8]; int2 mycv[8];
#pragma unroll
    for (int k = 0; k < 8; k++) {
        int e = base + k * 256 + t;
        myb[k] = -1;
        if (e < S.etot) {
            int r; unsigned c; float v;
            fetch_edge(S, e, r, c, v);
            int b = r >> CSHIFT;
            mycv[k] = make_int2((int)(((unsigned)(r & (RALIGN - 1)) << 19) | c),
                                __float_as_int(v));
            myb[k] = b;
            myrank[k] = atomicAdd(&cnt[b], 1);
        }
    }
    __syncthreads();
    if (cnt[t] > 0) gb[t] = atomicAdd(&cfront[t], cnt[t]);
    __syncthreads();
#pragma unroll
    for (int k = 0; k < 8; k++)
        if (myb[k] >= 0) stg1[gb[myb[k]] + myrank[k]] = mycv[k];
}

// ---- mid histogram from coarse-sorted staging (windowed LDS counters) ----
__global__ __launch_bounds__(256) void hist_mid(
    const int2* __restrict__ stg1, const int* __restrict__ cbase_g,
    int* __restrict__ mcnt, int E, int NBc)
{
    __shared__ int cb[258];
    __shared__ int wc[MWIN];
    int t = threadIdx.x;
    for (int i = t; i <= NBc; i += 256) cb[i] = cbase_g[i];
    for (int i = t; i < MWIN; i += 256) wc[i] = 0;
    __syncthreads();
    int base = blockIdx.x * TILE_E;
    int lo = 0, hi = NBc - 1;
    while (lo < hi) { int m = (lo + hi + 1) >> 1; if (cb[m] <= base) lo = m; else hi = m - 1; }
    int winm = lo * MPC;
#pragma unroll
    for (int k = 0; k < 8; k++) {
        int e = base + k * 256 + t;
        if (e < E) {
            int b = lo;
            while (cb[b + 1] <= e) b++;
            int m = b * MPC + (int)(((unsigned)stg1[e].x >> 19) >> MSHIFT);
            int lf = m - winm;
            if (lf >= 0 && lf < MWIN) atomicAdd(&wc[lf], 1);
            else atomicAdd(&mcnt[m], 1);    // rare fallback
        }
    }
    __syncthreads();
    for (int i = t; i < MWIN; i += 256)
        if (wc[i] > 0) atomicAdd(&mcnt[winm + i], wc[i]);
}

// ---- parallel scan over mid buckets: one wave per coarse bucket (64 mids each);
//      global carry is cbase[b], so no cross-block dependency ----
__global__ __launch_bounds__(64) void scan_mid_par(
    const int* __restrict__ mcnt, const int* __restrict__ cbase,
    int* __restrict__ mbase, int* __restrict__ mfront, int NBm, int E)
{
    int b = blockIdx.x, t = threadIdx.x;
    int m = (b << 6) + t;               // MPC == 64
    int v = (m < NBm) ? mcnt[m] : 0;
    int incl = v;
#pragma unroll
    for (int off = 1; off < 64; off <<= 1) {
        int x = __shfl_up(incl, off, 64);
        if (t >= off) incl += x;
    }
    if (m < NBm) {
        int ex = cbase[b] + incl - v;
        mbase[m] = ex; mfront[m] = ex;
    }
    if (b == (int)gridDim.x - 1 && t == 63) mbase[NBm] = E;
}

// ---- pass B: coarse-sorted staging -> mid (128-row) buckets; windowed LDS ranking ----
__global__ __launch_bounds__(256) void split_mid(
    const int2* __restrict__ stg1, const int* __restrict__ cbase_g,
    int* __restrict__ mfront, int2* __restrict__ stgm, int E, int NBc)
{
    __shared__ int cb[258];
    __shared__ int wc[MWIN], wg[MWIN];
    int t = threadIdx.x;
    for (int i = t; i <= NBc; i += 256) cb[i] = cbase_g[i];
    for (int i = t; i < MWIN; i += 256) wc[i] = 0;
    __syncthreads();
    int base = blockIdx.x * TILE_E;
    int lo = 0, hi = NBc - 1;
    while (lo < hi) { int m = (lo + hi + 1) >> 1; if (cb[m] <= base) lo = m; else hi = m - 1; }
    int winm = lo * MPC;
    int mylf[8], myrank[8]; int2 myp[8];
#pragma unroll
    for (int k = 0; k < 8; k++) {
        int e = base + k * 256 + t;
        mylf[k] = -1;
        if (e < E) {
            int b = lo;
            while (cb[b + 1] <= e) b++;
            int2 cv = stg1[e];
            int m = (b << (CSHIFT - MSHIFT)) + (int)(((unsigned)cv.x >> 19) >> MSHIFT);
            int lf = m - winm;
            if (lf >= 0 && lf < MWIN) { mylf[k] = lf; myrank[k] = atomicAdd(&wc[lf], 1); myp[k] = cv; }
            else stgm[atomicAdd(&mfront[m], 1)] = cv;   // rare fallback
        }
    }
    __syncthreads();
    for (int i = t; i < MWIN; i += 256)
        if (wc[i] > 0) wg[i] = atomicAdd(&mfront[winm + i], wc[i]);
    __syncthreads();
#pragma unroll
    for (int k = 0; k < 8; k++)
        if (mylf[k] >= 0) stgm[wg[mylf[k]] + myrank[k]] = myp[k];
}

// ---- pass C: one block per mid bucket; LDS counting sort to exact CSR ----
__global__ __launch_bounds__(256) void csr_sort(
    const int2* __restrict__ stgm, const int* __restrict__ mbase,
    int* __restrict__ rowptr, int2* __restrict__ ecv, int N)
{
    __shared__ int2 buf[CAP];
    __shared__ int cnt[128], sc[128], front[128];
    int mb = blockIdx.x, t = threadIdx.x;
    int row0 = mb << MSHIFT;
    int nrows = N - row0; if (nrows > 128) nrows = 128;
    int s = mbase[mb], eend = mbase[mb + 1];
    if (t < 128) cnt[t] = 0;
    __syncthreads();
    for (int i = s + t; i < eend; i += 256)
        atomicAdd(&cnt[((unsigned)stgm[i].x >> 19) & 127], 1);
    __syncthreads();
    if (t < 128) sc[t] = cnt[t];
    __syncthreads();
    for (int off = 1; off < 128; off <<= 1) {
        int x = (t >= off && t < 128) ? sc[t - off] : 0;
        __syncthreads();
        if (t < 128) sc[t] += x;
        __syncthreads();
    }
    if (t < 128) front[t] = sc[t] - cnt[t];
    if (t < nrows) rowptr[row0 + t] = s + sc[t] - cnt[t];
    if (t == 0 && row0 + nrows == N) rowptr[N] = eend;
    __syncthreads();
    for (int i = s + t; i < eend; i += 256) {
        int2 cv = stgm[i];
        unsigned p = (unsigned)cv.x;
        int rl = ((int)(p >> 19)) & 127;
        int2 rec = make_int2((int)(p & 0x7FFFFu), cv.y);
        int l = atomicAdd(&front[rl], 1);
        if (l < CAP) buf[l] = rec;
        else ecv[s + l] = rec;               // overflow fallback (statistically never)
    }
    __syncthreads();
    int total = eend - s; if (total > CAP) total = CAP;
    for (int l = t; l < total; l += 256) ecv[s + l] = buf[l];
}

// ======================= batched (3-dim) compute kernels =======================

struct DArgs {
    const float *in0, *in1, *in2;
    const float *W0, *W1, *W2;
    const float *bb0, *bb1, *bb2;
    float *H0, *H1, *H2;
    half_t *Z0, *Z1, *Z2;
    int n0, n1, n2;
    int base1, base2;
};

// H[n,:] = act(in[n,:]) @ W[0:32,:] + b (stride HS); Z[n,:] = act(in[n,:]) @ W[32:64,:] (fp16, stride ZS)
template<int COUT, bool LRELU, int HS, int ZS>
__global__ __launch_bounds__(256) void dense_kernel(DArgs A)
{
    int bid = blockIdx.x;
    int d = (bid >= A.base1 ? 1 : 0) + (bid >= A.base2 ? 1 : 0);
    int bb = d == 0 ? 0 : (d == 1 ? A.base1 : A.base2);
    int nd = d == 0 ? A.n0 : (d == 1 ? A.n1 : A.n2);
    const float* in = d == 0 ? A.in0 : (d == 1 ? A.in1 : A.in2);
    const float* W  = d == 0 ? A.W0  : (d == 1 ? A.W1  : A.W2);
    const float* b  = d == 0 ? A.bb0 : (d == 1 ? A.bb1 : A.bb2);
    float* H        = d == 0 ? A.H0  : (d == 1 ? A.H1  : A.H2);
    half_t* Z       = d == 0 ? A.Z0  : (d == 1 ? A.Z1  : A.Z2);
    int n = (bid - bb) * 256 + threadIdx.x;
    if (n >= nd) return;
    const float* row = in + (size_t)n * 32;
    float xv[32];
#pragma unroll
    for (int f = 0; f < 32; f += 4) {
        float4 v = *(const float4*)(row + f);
        xv[f] = v.x; xv[f + 1] = v.y; xv[f + 2] = v.z; xv[f + 3] = v.w;
    }
    if (LRELU) {
#pragma unroll
        for (int f = 0; f < 32; f++) xv[f] = xv[f] > 0.f ? xv[f] : NEG_SLOPE * xv[f];
    }
    float acct[COUT], accb[COUT];
#pragma unroll
    for (int c = 0; c < COUT; c++) { acct[c] = b[c]; accb[c] = 0.f; }
#pragma unroll 4
    for (int f = 0; f < 32; f++) {
        float xf = xv[f];
#pragma unroll
        for (int c = 0; c < COUT; c++) {
            acct[c] = fmaf(xf, W[f * COUT + c], acct[c]);
            accb[c] = fmaf(xf, W[(32 + f) * COUT + c], accb[c]);
        }
    }
    float* hrow = H + (size_t)n * HS;
    half_t* zrow = Z + (size_t)n * ZS;
#pragma unroll
    for (int c = 0; c < COUT; c += 2)
        *(float2*)(hrow + c) = make_float2(acct[c], acct[c + 1]);
#pragma unroll
    for (int c = 0; c < COUT; c += 2) {
        half2_t h;
        h.x = (half_t)accb[c];
        h.y = (half_t)accb[c + 1];
        *(half2_t*)(zrow + c) = h;
    }
}

struct GArgs {
    const int *rp0, *rp1, *rp2;
    const half_t *Z0, *Z1, *Z2;
    float *H0, *H1, *H2;
    int n0, n1, n2;
    int base1, base2;
};

// CSR gather, 2 interleaved row-chains per thread (C=32, 8 lanes x half4) — 20 VGPR class
__global__ __launch_bounds__(256) void gather32(GArgs A, const int2* __restrict__ ecv)
{
    int bid = blockIdx.x;
    int d = (bid >= A.base1 ? 1 : 0) + (bid >= A.base2 ? 1 : 0);
    int bb = d == 0 ? 0 : (d == 1 ? A.base1 : A.base2);
    int nd = d == 0 ? A.n0 : (d == 1 ? A.n1 : A.n2);
    const int* rowptr = d == 0 ? A.rp0 : (d == 1 ? A.rp1 : A.rp2);
    const half_t* Z   = d == 0 ? A.Z0  : (d == 1 ? A.Z1  : A.Z2);
    float* H          = d == 0 ? A.H0  : (d == 1 ? A.H1  : A.H2);
    int tid = (bid - bb) * 256 + threadIdx.x;
    int pr = tid >> 3, lane = tid & 7;
    int r0 = pr * 2, r1 = r0 + 1;
    if (r0 >= nd) return;
    int s0 = rowptr[r0], e0 = rowptr[r0 + 1];
    int s1 = 0, e1 = 0;
    if (r1 < nd) { s1 = rowptr[r1]; e1 = rowptr[r1 + 1]; }
    float ax0 = 0.f, ay0 = 0.f, az0 = 0.f, aw0 = 0.f;
    float ax1 = 0.f, ay1 = 0.f, az1 = 0.f, aw1 = 0.f;
    int i0 = s0, i1 = s1;
    while (i0 < e0 && i1 < e1) {
        int2 c0 = ecv[i0]; int2 c1 = ecv[i1];
        half4_t z0 = *(const half4_t*)(Z + (size_t)c0.x * 32 + lane * 4);
        half4_t z1 = *(const half4_t*)(Z + (size_t)c1.x * 32 + lane * 4);
        float v0 = __int_as_float(c0.y), v1 = __int_as_float(c1.y);
        ax0 = fmaf(v0, (float)z0.x, ax0); ay0 = fmaf(v0, (float)z0.y, ay0);
        az0 = fmaf(v0, (float)z0.z, az0); aw0 = fmaf(v0, (float)z0.w, aw0);
        ax1 = fmaf(v1, (float)z1.x, ax1); ay1 = fmaf(v1, (float)z1.y, ay1);
        az1 = fmaf(v1, (float)z1.z, az1); aw1 = fmaf(v1, (float)z1.w, aw1);
        i0++; i1++;
    }
    for (; i0 < e0; i0++) {
        int2 c0 = ecv[i0];
        half4_t z0 = *(const half4_t*)(Z + (size_t)c0.x * 32 + lane * 4);
        float v0 = __int_as_float(c0.y);
        ax0 = fmaf(v0, (float)z0.x, ax0); ay0 = fmaf(v0, (float)z0.y, ay0);
        az0 = fmaf(v0, (float)z0.z, az0); aw0 = fmaf(v0, (float)z0.w, aw0);
    }
    for (; i1 < e1; i1++) {
        int2 c1 = ecv[i1];
        half4_t z1 = *(const half4_t*)(Z + (size_t)c1.x * 32 + lane * 4);
        float v1 = __int_as_float(c1.y);
        ax1 = fmaf(v1, (float)z1.x, ax1); ay1 = fmaf(v1, (float)z1.y, ay1);
        az1 = fmaf(v1, (float)z1.z, az1); aw1 = fmaf(v1, (float)z1.w, aw1);
    }
    float4* hp0 = (float4*)(H + (size_t)r0 * 32 + lane * 4);
    float4 h0 = *hp0;
    h0.x += ax0; h0.y += ay0; h0.z += az0; h0.w += aw0;
    *hp0 = h0;
    if (r1 < nd) {
        float4* hp1 = (float4*)(H + (size_t)r1 * 32 + lane * 4);
        float4 h1 = *hp1;
        h1.x += ax1; h1.y += ay1; h1.z += az1; h1.w += aw1;
        *hp1 = h1;
    }
}

// C=10 final gather: Z packed stride 16 halfs, H packed stride 16 floats, RMW (no atomics)
__global__ __launch_bounds__(256) void gather10(GArgs A, const int2* __restrict__ ecv)
{
    int bid = blockIdx.x;
    int d = (bid >= A.base1 ? 1 : 0) + (bid >= A.base2 ? 1 : 0);
    int bb = d == 0 ? 0 : (d == 1 ? A.base1 : A.base2);
    int nd = d == 0 ? A.n0 : (d == 1 ? A.n1 : A.n2);
    const int* rowptr = d == 0 ? A.rp0 : (d == 1 ? A.rp1 : A.rp2);
    const half_t* Z   = d == 0 ? A.Z0  : (d == 1 ? A.Z1  : A.Z2);
    float* H          = d == 0 ? A.H0  : (d == 1 ? A.H1  : A.H2);
    int tid = (bid - bb) * 256 + threadIdx.x;
    int pr = tid >> 3, lane = tid & 7;
    int r0 = pr * 2, r1 = r0 + 1;
    if (r0 >= nd || lane >= 5) return;
    int s0 = rowptr[r0], e0 = rowptr[r0 + 1];
    int s1 = 0, e1 = 0;
    if (r1 < nd) { s1 = rowptr[r1]; e1 = rowptr[r1 + 1]; }
    float ax0 = 0.f, ay0 = 0.f, ax1 = 0.f, ay1 = 0.f;
    int i0 = s0, i1 = s1;
    while (i0 < e0 && i1 < e1) {
        int2 c0 = ecv[i0]; int2 c1 = ecv[i1];
        half2_t z0 = *(const half2_t*)(Z + (size_t)c0.x * 16 + lane * 2);
        half2_t z1 = *(const half2_t*)(Z + (size_t)c1.x * 16 + lane * 2);
        float v0 = __int_as_float(c0.y), v1 = __int_as_float(c1.y);
        ax0 = fmaf(v0, (float)z0.x, ax0); ay0 = fmaf(v0, (float)z0.y, ay0);
        ax1 = fmaf(v1, (float)z1.x, ax1); ay1 = fmaf(v1, (float)z1.y, ay1);
        i0++; i1++;
    }
    for (; i0 < e0; i0++) {
        int2 c0 = ecv[i0];
        half2_t z0 = *(const half2_t*)(Z + (size_t)c0.x * 16 + lane * 2);
        float v0 = __int_as_float(c0.y);
        ax0 = fmaf(v0, (float)z0.x, ax0); ay0 = fmaf(v0, (float)z0.y, ay0);
    }
    for (; i1 < e1; i1++) {
        int2 c1 = ecv[i1];
        half2_t z1 = *(const half2_t*)(Z + (size_t)c1.x * 16 + lane * 2);
        float v1 = __int_as_float(c1.y);
        ax1 = fmaf(v1, (float)z1.x, ax1); ay1 = fmaf(v1, (float)z1.y, ay1);
    }
    float* hp0 = H + (size_t)r0 * 16 + lane * 2;
    hp0[0] += ax0; hp0[1] += ay0;
    if (r1 < nd) {
        float* hp1 = H + (size_t)r1 * 16 + lane * 2;
        hp1[0] += ax1; hp1[1] += ay1;
    }
}

struct PArgs {
    const float *H0, *H1, *H2;
    const int *bt0, *bt1, *bt2;
    int n0, n1, n2;
};

// 3*G blocks: block -> (dim, graph); batch sorted -> binary search, no atomics; H stride 16
__global__ __launch_bounds__(256) void pool_graph(PArgs A, float* __restrict__ pool, int G)
{
    int bid = blockIdx.x;
    int d = (bid >= G ? 1 : 0) + (bid >= 2 * G ? 1 : 0);
    int g = bid - d * G;
    const float* H = d == 0 ? A.H0 : (d == 1 ? A.H1 : A.H2);
    const int* batch = d == 0 ? A.bt0 : (d == 1 ? A.bt1 : A.bt2);
    int N = d == 0 ? A.n0 : (d == 1 ? A.n1 : A.n2);
    int lo = 0, hi = N;
    while (lo < hi) { int mid = (lo + hi) >> 1; if (batch[mid] < g) lo = mid + 1; else hi = mid; }
    int start = lo;
    lo = start; hi = N;
    while (lo < hi) { int mid = (lo + hi) >> 1; if (batch[mid] < g + 1) lo = mid + 1; else hi = mid; }
    int end = lo;
    int t = threadIdx.x, f = t & 15, chain = t >> 4;
    __shared__ float sd[256];
    float acc = 0.f;
    if (f < 10) {
        for (int i = start + chain; i < end; i += 16) acc += H[(size_t)i * 16 + f];
    }
    sd[t] = acc; __syncthreads();
    if (chain == 0 && f < 10) {
        float s = 0.f;
#pragma unroll
        for (int k = 0; k < 16; k++) s += sd[k * 16 + f];
        int c = end - start;
        float inv = 1.f / (float)(c > 1 ? c : 1);
        pool[(size_t)g * 30 + d * 10 + f] = s * inv;
    }
}

__global__ __launch_bounds__(256) void final_kernel(
    const float* __restrict__ pool, const float* __restrict__ Wf,
    const float* __restrict__ bfv, float* __restrict__ out, int G)
{
    int g = blockIdx.x * 256 + threadIdx.x;
    if (g >= G) return;
    float m[30];
#pragma unroll
    for (int j = 0; j < 30; j++) m[j] = pool[(size_t)g * 30 + j];
    float lg[10];
#pragma unroll
    for (int o = 0; o < 10; o++) {
        float a = bfv[o];
#pragma unroll
        for (int j = 0; j < 30; j++) a = fmaf(m[j], Wf[j * 10 + o], a);
        lg[o] = a;
    }
    float mx = lg[0];
#pragma unroll
    for (int o = 1; o < 10; o++) mx = fmaxf(mx, lg[o]);
    float s = 0.f;
#pragma unroll
    for (int o = 0; o < 10; o++) { lg[o] = __expf(lg[o] - mx); s += lg[o]; }
    float invs = 1.f / s;
#pragma unroll
    for (int o = 0; o < 10; o++) out[(size_t)g * 10 + o] = lg[o] * invs;
}

extern "C" void kernel_launch(void* const* d_in, const int* in_sizes, int n_in,
                              void* d_out, int out_size, void* d_ws, size_t ws_size,
                              hipStream_t stream)
{
    (void)n_in;
    const float* x[3]    = {(const float*)d_in[0], (const float*)d_in[1], (const float*)d_in[2]};
    const float* vals[3] = {(const float*)d_in[3], (const float*)d_in[4], (const float*)d_in[5]};
    const int* rows[3]   = {(const int*)d_in[6], (const int*)d_in[8], (const int*)d_in[10]};
    const int* cols[3]   = {(const int*)d_in[7], (const int*)d_in[9], (const int*)d_in[11]};
    const int* batch[3]  = {(const int*)d_in[12], (const int*)d_in[13], (const int*)d_in[14]};
    const float* W1[3] = {(const float*)d_in[16], (const float*)d_in[22], (const float*)d_in[28]};
    const float* b1[3] = {(const float*)d_in[17], (const float*)d_in[23], (const float*)d_in[29]};
    const float* W2[3] = {(const float*)d_in[18], (const float*)d_in[24], (const float*)d_in[30]};
    const float* b2[3] = {(const float*)d_in[19], (const float*)d_in[25], (const float*)d_in[31]};
    const float* W3[3] = {(const float*)d_in[20], (const float*)d_in[26], (const float*)d_in[32]};
    const float* b3[3] = {(const float*)d_in[21], (const float*)d_in[27], (const float*)d_in[33]};
    const float* Wf  = (const float*)d_in[34];
    const float* bfv = (const float*)d_in[35];
    float* out = (float*)d_out;

    int N[3] = {in_sizes[0] / 32, in_sizes[1] / 32, in_sizes[2] / 32};
    int E[3] = {in_sizes[3], in_sizes[4], in_sizes[5]};
    int G = out_size / 10;
    int maxN = N[0]; if (N[1] > maxN) maxN = N[1]; if (N[2] > maxN) maxN = N[2];
    int maxE = E[0]; if (E[1] > maxE) maxE = E[1]; if (E[2] > maxE) maxE = E[2];

    // union (bucket-aligned) row offsets; cols stay LOCAL everywhere
    int o1 = cdiv(N[0], RALIGN) * RALIGN;
    int o2 = o1 + cdiv(N[1], RALIGN) * RALIGN;
    int NU = o2 + N[2];
    long long EU = (long long)E[0] + E[1] + E[2];
    int NBcU = cdiv(NU, RALIGN);
    int NBmU = cdiv(NU, 1 << MSHIFT);
    size_t sumN = (size_t)N[0] + N[1] + N[2];
    size_t pN[3] = {0, (size_t)N[0], (size_t)N[0] + N[1]};
    int offsU[3] = {0, o1, o2};

    char* base = (char*)d_ws;

    // ---- batched layout ----
    // [0, regC): build stg1[EU] + stgm[EU] / compute bufA3(sumN*128B) + bufZ3(sumN*64B)
    size_t regC = al16((size_t)2 * EU * 8 > sumN * 192 ? (size_t)2 * EU * 8 : sumN * 192);
    size_t off_z3  = regC;                                  // Z3p packed: sumN*32 B
    size_t off_ecv = al16(off_z3 + sumN * 32);
    size_t off_rp  = off_ecv + (size_t)EU * 8;
    size_t off_cnt = al16(off_rp + ((size_t)NU + 1) * 4);
    size_t cnt_ints = (size_t)3 * NBmU + 1 + 256 + 258 + 256;
    size_t off_pool = al16(off_cnt + cnt_ints * 4);
    size_t need = off_pool + (size_t)G * 30 * 4;
    bool batched = (need <= ws_size);

    if (batched) {
        int2* stg1 = (int2*)base;
        int2* stgm = (int2*)(base + (size_t)EU * 8);
        float* bufA3 = (float*)base;
        half_t* bufZ3 = (half_t*)(base + sumN * 128);
        float* H3p3 = (float*)(base + sumN * 128);          // replaces Z1/Z2 region at layer 3
        half_t* Z3p3 = (half_t*)(base + off_z3);
        int2* ecv = (int2*)(base + off_ecv);
        int* rowptrU = (int*)(base + off_rp);
        int* mcnt = (int*)(base + off_cnt);
        int* mbase = mcnt + NBmU;
        int* mfront = mbase + NBmU + 1;
        int* ccnt = mfront + NBmU;
        int* cbase = ccnt + 256;
        int* cfront = cbase + 258;
        float* pool = (float*)(base + off_pool);

        // ---- ONE union build for all 3 dims ----
        Src3 S;
        S.r0 = rows[0]; S.c0 = cols[0]; S.v0 = vals[0];
        S.r1 = rows[1]; S.c1 = cols[1]; S.v1 = vals[1];
        S.r2 = rows[2]; S.c2 = cols[2]; S.v2 = vals[2];
        S.e1 = E[0]; S.e2 = E[0] + E[1]; S.etot = (int)EU;
        S.o1 = o1; S.o2 = o2;
        int ntileU = cdiv(EU, TILE_E);
        int zlenU = 3 * NBmU + 257;     // mcnt + mbase + mfront + ccnt (contiguous)
        zero_i32<<<cdiv(zlenU, 256), 256, 0, stream>>>(mcnt, zlenU);
        hist_coarse<<<ntileU, 256, 0, stream>>>(S, ccnt);
        scan_coarse<<<1, 64, 0, stream>>>(ccnt, cbase, cfront, NBcU, (int)EU);
        split_coarse<<<ntileU, 256, 0, stream>>>(S, cfront, stg1);
        hist_mid<<<ntileU, 256, 0, stream>>>(stg1, cbase, mcnt, (int)EU, NBcU);
        scan_mid_par<<<NBcU, 64, 0, stream>>>(mcnt, cbase, mbase, mfront, NBmU, (int)EU);
        split_mid<<<ntileU, 256, 0, stream>>>(stg1, cbase, mfront, stgm, (int)EU, NBcU);
        csr_sort<<<NBmU, 256, 0, stream>>>(stgm, mbase, rowptrU, ecv, NU);

        // ---- per-layer batched compute across all 3 dims ----
        int nb[3], gb[3];
        for (int d = 0; d < 3; d++) {
            nb[d] = cdiv(N[d], 256);
            gb[d] = cdiv((long long)cdiv(N[d], 2) * 8, 256);
        }
        DArgs D;
        D.in0 = x[0]; D.in1 = x[1]; D.in2 = x[2];
        D.W0 = W1[0]; D.W1 = W1[1]; D.W2 = W1[2];
        D.bb0 = b1[0]; D.bb1 = b1[1]; D.bb2 = b1[2];
        D.H0 = bufA3 + pN[0] * 32; D.H1 = bufA3 + pN[1] * 32; D.H2 = bufA3 + pN[2] * 32;
        D.Z0 = bufZ3 + pN[0] * 32; D.Z1 = bufZ3 + pN[1] * 32; D.Z2 = bufZ3 + pN[2] * 32;
        D.n0 = N[0]; D.n1 = N[1]; D.n2 = N[2];
        D.base1 = nb[0]; D.base2 = nb[0] + nb[1];
        int nbsum = nb[0] + nb[1] + nb[2];

        GArgs Gg;
        Gg.rp0 = rowptrU + offsU[0]; Gg.rp1 = rowptrU + offsU[1]; Gg.rp2 = rowptrU + offsU[2];
        Gg.Z0 = D.Z0; Gg.Z1 = D.Z1; Gg.Z2 = D.Z2;
        Gg.H0 = D.H0; Gg.H1 = D.H1; Gg.H2 = D.H2;
        Gg.n0 = N[0]; Gg.n1 = N[1]; Gg.n2 = N[2];
        Gg.base1 = gb[0]; Gg.base2 = gb[0] + gb[1];
        int gbsum = gb[0] + gb[1] + gb[2];

        dense_kernel<32, false, 32, 32><<<nbsum, 256, 0, stream>>>(D);
        gather32<<<gbsum, 256, 0, stream>>>(Gg, ecv);
        D.in0 = D.H0; D.in1 = D.H1; D.in2 = D.H2;
        D.W0 = W2[0]; D.W1 = W2[1]; D.W2 = W2[2];
        D.bb0 = b2[0]; D.bb1 = b2[1]; D.bb2 = b2[2];
        dense_kernel<32, true, 32, 32><<<nbsum, 256, 0, stream>>>(D);
        gather32<<<gbsum, 256, 0, stream>>>(Gg, ecv);
        // layer 3: packed H (stride 16 f32, in old Z region) + packed Z (stride 16 half)
        DArgs D3 = D;
        D3.W0 = W3[0]; D3.W1 = W3[1]; D3.W2 = W3[2];
        D3.bb0 = b3[0]; D3.bb1 = b3[1]; D3.bb2 = b3[2];
        D3.H0 = H3p3 + pN[0] * 16; D3.H1 = H3p3 + pN[1] * 16; D3.H2 = H3p3 + pN[2] * 16;
        D3.Z0 = Z3p3 + pN[0] * 16; D3.Z1 = Z3p3 + pN[1] * 16; D3.Z2 = Z3p3 + pN[2] * 16;
        dense_kernel<10, true, 16, 16><<<nbsum, 256, 0, stream>>>(D3);
        GArgs G10 = Gg;
        G10.Z0 = D3.Z0; G10.Z1 = D3.Z1; G10.Z2 = D3.Z2;
        G10.H0 = D3.H0; G10.H1 = D3.H1; G10.H2 = D3.H2;
        gather10<<<gbsum, 256, 0, stream>>>(G10, ecv);
        PArgs P;
        P.H0 = D3.H0; P.H1 = D3.H1; P.H2 = D3.H2;
        P.bt0 = batch[0]; P.bt1 = batch[1]; P.bt2 = batch[2];
        P.n0 = N[0]; P.n1 = N[1]; P.n2 = N[2];
        pool_graph<<<3 * G, 256, 0, stream>>>(P, pool, G);
        final_kernel<<<cdiv(G, 256), 256, 0, stream>>>(pool, Wf, bfv, out, G);
    } else {
        // ---- fallback: per-dim build + compute (R5-equivalent layout), same kernels ----
        int maxNBm = cdiv(maxN, 1 << MSHIFT);
        float* bufA = (float*)base;
        half_t* bufZh = (half_t*)(base + (size_t)maxN * 128);
        float* H3p = (float*)(base + (size_t)maxN * 128);
        half_t* Z3p = (half_t*)(base + (size_t)maxN * 128 + (size_t)maxN * 64);
        float* pool = (float*)(base + (size_t)maxN * 256);
        int2* ecv = (int2*)(base + al16((size_t)maxN * 256 + (size_t)G * 30 * 4));
        int* rowptr = (int*)(ecv + maxE);
        int* mcnt = rowptr + (maxN + 1);
        int* mbase = mcnt + maxNBm;
        int* mfront = mbase + (maxNBm + 1);
        int* ccnt = mfront + maxNBm;
        int* cbase = ccnt + 256;
        int* cfront = cbase + 258;
        int2* stg1 = (int2*)bufA;
        int2* stgm = (int2*)(base + (size_t)maxN * 128);
        int zlen = 3 * maxNBm + 257;
        for (int d = 0; d < 3; d++) {
            int n = N[d], e = E[d];
            int NBc = cdiv(n, RALIGN);
            int NBm = cdiv(n, 1 << MSHIFT);
            int ntile = cdiv(e, TILE_E);
            int nb = cdiv(n, 256);
            int gbl = cdiv((long long)cdiv(n, 2) * 8, 256);
            Src3 S;
            S.r0 = rows[d]; S.c0 = cols[d]; S.v0 = vals[d];
            S.r1 = rows[d]; S.c1 = cols[d]; S.v1 = vals[d];
            S.r2 = rows[d]; S.c2 = cols[d]; S.v2 = vals[d];
            S.e1 = e; S.e2 = e; S.etot = e; S.o1 = 0; S.o2 = 0;
            zero_i32<<<cdiv(zlen, 256), 256, 0, stream>>>(mcnt, zlen);
            hist_coarse<<<ntile, 256, 0, stream>>>(S, ccnt);
            scan_coarse<<<1, 64, 0, stream>>>(ccnt, cbase, cfront, NBc, e);
            split_coarse<<<ntile, 256, 0, stream>>>(S, cfront, stg1);
            hist_mid<<<ntile, 256, 0, stream>>>(stg1, cbase, mcnt, e, NBc);
            scan_mid_par<<<NBc, 64, 0, stream>>>(mcnt, cbase, mbase, mfront, NBm, e);
            split_mid<<<ntile, 256, 0, stream>>>(stg1, cbase, mfront, stgm, e, NBc);
            csr_sort<<<NBm, 256, 0, stream>>>(stgm, mbase, rowptr, ecv, n);

            DArgs D;
            D.in0 = x[d]; D.in1 = x[d]; D.in2 = x[d];
            D.W0 = W1[d]; D.W1 = W1[d]; D.W2 = W1[d];
            D.bb0 = b1[d]; D.bb1 = b1[d]; D.bb2 = b1[d];
            D.H0 = bufA; D.H1 = bufA; D.H2 = bufA;
            D.Z0 = bufZh; D.Z1 = bufZh; D.Z2 = bufZh;
            D.n0 = n; D.n1 = n; D.n2 = n;
            D.base1 = nb; D.base2 = nb;
            GArgs Gg;
            Gg.rp0 = rowptr; Gg.rp1 = rowptr; Gg.rp2 = rowptr;
            Gg.Z0 = bufZh; Gg.Z1 = bufZh; Gg.Z2 = bufZh;
            Gg.H0 = bufA; Gg.H1 = bufA; Gg.H2 = bufA;
            Gg.n0 = n; Gg.n1 = n; Gg.n2 = n;
            Gg.base1 = gbl; Gg.base2 = gbl;
            dense_kernel<32, false, 32, 32><<<nb, 256, 0, stream>>>(D);
            gather32<<<gbl, 256, 0, stream>>>(Gg, ecv);
            D.in0 = bufA; D.in1 = bufA; D.in2 = bufA;
            D.W0 = W2[d]; D.W1 = W2[d]; D.W2 = W2[d];
            D.bb0 = b2[d]; D.bb1 = b2[d]; D.bb2 = b2[d];
            dense_kernel<32, true, 32, 32><<<nb, 256, 0, stream>>>(D);
            gather32<<<gbl, 256, 0, stream>>>(Gg, ecv);
            DArgs D3 = D;
            D3.W0 = W3[d]; D3.W1 = W3[d]; D3.W2 = W3[d];
            D3.bb0 = b3[d]; D3.bb1 = b3[d]; D3.bb2 = b3[d];
            D3.H0 = H3p; D3.H1 = H3p; D3.H2 = H3p;
            D3.Z0 = Z3p; D3.Z1 = Z3p; D3.Z2 = Z3p;
            dense_kernel<10, true, 16, 16><<<nb, 256, 0, stream>>>(D3);
            GArgs G10 = Gg;
            G10.Z0 = Z3p; G10.Z1 = Z3p; G10.Z2 = Z3p;
            G10.H0 = H3p; G10.H1 = H3p; G10.H2 = H3p;
            gather10<<<gbl, 256, 0, stream>>>(G10, ecv);
            PArgs P;
            P.H0 = H3p; P.H1 = H3p; P.H2 = H3p;
            P.bt0 = batch[d]; P.bt1 = batch[d]; P.bt2 = batch[d];
            P.n0 = n; P.n1 = n; P.n2 = n;
            // G-block launch => in-kernel d==0; offset pool base by d*10 so each dim
            // lands in its [g*30 + d*10 + f] slot (bug fixed vs R8 submission)
            pool_graph<<<G, 256, 0, stream>>>(P, pool + (size_t)d * 10, G);
        }
        final_kernel<<<cdiv(G, 256), 256, 0, stream>>>(pool, Wf, bfv, out, G);
    }
}

// Round 10
// 1104.819 us; speedup vs baseline: 1.3996x; 1.0693x over previous
//
#include <hip/hip_runtime.h>
#include <stdint.h>

#define NEG_SLOPE 0.01f
#define CSHIFT 13               // 8192 rows per coarse bucket
#define RALIGN (1 << CSHIFT)
#define MSHIFT 7                // 128 rows per mid bucket
#define MPC (1 << (CSHIFT - MSHIFT))   // 64 mids per coarse
#define MWIN 192                // window of mid-counters per split tile (straddle<=2 coarse)
#define CAP 4096                // max edges per mid bucket in csr_sort LDS
#define TILE_E 2048             // edges per split tile

typedef _Float16 half_t;
typedef _Float16 half2_t __attribute__((ext_vector_type(2)));
typedef _Float16 half4_t __attribute__((ext_vector_type(4)));

static inline int cdiv(long long a, long long b) { return (int)((a + b - 1) / b); }
static inline size_t al16(size_t x) { return (x + 15) & ~(size_t)15; }

// up to 3 edge sources concatenated: [0,e1) dim0 (+0), [e1,e2) dim1 (+o1), [e2,etot) dim2 (+o2)
struct Src3 {
    const int* r0; const int* c0; const float* v0;
    const int* r1; const int* c1; const float* v1;
    const int* r2; const int* c2; const float* v2;
    int e1, e2, etot;
    int o1, o2;
};

__device__ __forceinline__ int fetch_row(const Src3& S, int e) {
    if (e < S.e1) return S.r0[e];
    if (e < S.e2) return S.r1[e - S.e1] + S.o1;
    return S.r2[e - S.e2] + S.o2;
}
__device__ __forceinline__ void fetch_edge(const Src3& S, int e, int& r, unsigned& c, float& v) {
    if (e < S.e1) { r = S.r0[e]; c = (unsigned)S.c0[e]; v = S.v0[e]; }
    else if (e < S.e2) { int i = e - S.e1; r = S.r1[i] + S.o1; c = (unsigned)S.c1[i]; v = S.v1[i]; }
    else { int i = e - S.e2; r = S.r2[i] + S.o2; c = (unsigned)S.c2[i]; v = S.v2[i]; }
}

__global__ __launch_bounds__(256) void zero_i32(int* __restrict__ p, int n) {
    int i = blockIdx.x * 256 + threadIdx.x;
    if (i < n) p[i] = 0;
}

// ---- coarse histogram: LDS counters (<=256 buckets), one merge atomic per (block,bucket) ----
__global__ __launch_bounds__(256) void hist_coarse(Src3 S, int* __restrict__ ccnt) {
    __shared__ int cnt[256];
    int t = threadIdx.x;
    cnt[t] = 0;
    __syncthreads();
    int base = blockIdx.x * TILE_E;
#pragma unroll
    for (int k = 0; k < TILE_E / 256; k++) {
        int e = base + k * 256 + t;
        if (e < S.etot) atomicAdd(&cnt[fetch_row(S, e) >> CSHIFT], 1);
    }
    __syncthreads();
    if (cnt[t] > 0) atomicAdd(&ccnt[t], cnt[t]);
}

__global__ void scan_coarse(const int* __restrict__ ccnt, int* __restrict__ cbase,
                            int* __restrict__ cfront, int NBc, int E) {
    if (threadIdx.x == 0 && blockIdx.x == 0) {
        int run = 0;
        for (int b = 0; b < NBc; b++) { cbase[b] = run; cfront[b] = run; run += ccnt[b]; }
        cbase[NBc] = E;
    }
}

// ---- pass A: LDS multisplit into coarse buckets; dense chunk writes ----
// record: ( (row & 8191) << 19 | col_local , val )
__global__ __launch_bounds__(256) void split_coarse(
    Src3 S, int* __restrict__ cfront, int2* __restrict__ stg1)
{
    __shared__ int cnt[256], gb[256];
    int t = threadIdx.x;
    cnt[t] = 0;
    __syncthreads();
    int base = blockIdx.x * TILE_E;
    int myb[8], myrank[8]; int2 mycv[8];
#pragma unroll
    for (int k = 0; k < 8; k++) {
        int e = base + k * 256 + t;
        myb[k] = -1;
        if (e < S.etot) {
            int r; unsigned c; float v;
            fetch_edge(S, e, r, c, v);
            int b = r >> CSHIFT;
            mycv[k] = make_int2((int)(((unsigned)(r & (RALIGN - 1)) << 19) | c),
                                __float_as_int(v));
            myb[k] = b;
            myrank[k] = atomicAdd(&cnt[b], 1);
        }
    }
    __syncthreads();
    if (cnt[t] > 0) gb[t] = atomicAdd(&cfront[t], cnt[t]);
    __syncthreads();
#pragma unroll
    for (int k = 0; k < 8; k++)
        if (myb[k] >= 0) stg1[gb[myb[k]] + myrank[k]] = mycv[k];
}

// ---- mid histogram from coarse-sorted staging (windowed LDS counters) ----
__global__ __launch_bounds__(256) void hist_mid(
    const int2* __restrict__ stg1, const int* __restrict__ cbase_g,
    int* __restrict__ mcnt, int E, int NBc)
{
    __shared__ int cb[258];
    __shared__ int wc[MWIN];
    int t = threadIdx.x;
    for (int i = t; i <= NBc; i += 256) cb[i] = cbase_g[i];
    for (int i = t; i < MWIN; i += 256) wc[i] = 0;
    __syncthreads();
    int base = blockIdx.x * TILE_E;
    int lo = 0, hi = NBc - 1;
    while (lo < hi) { int m = (lo + hi + 1) >> 1; if (cb[m] <= base) lo = m; else hi = m - 1; }
    int winm = lo * MPC;
#pragma unroll
    for (int k = 0; k < 8; k++) {
        int e = base + k * 256 + t;
        if (e < E) {
            int b = lo;
            while (cb[b + 1] <= e) b++;
            int m = b * MPC + (int)(((unsigned)stg1[e].x >> 19) >> MSHIFT);
            int lf = m - winm;
            if (lf >= 0 && lf < MWIN) atomicAdd(&wc[lf], 1);
            else atomicAdd(&mcnt[m], 1);    // rare fallback
        }
    }
    __syncthreads();
    for (int i = t; i < MWIN; i += 256)
        if (wc[i] > 0) atomicAdd(&mcnt[winm + i], wc[i]);
}

// ---- parallel scan over mid buckets: one wave per coarse bucket (64 mids each);
//      global carry is cbase[b], so no cross-block dependency ----
__global__ __launch_bounds__(64) void scan_mid_par(
    const int* __restrict__ mcnt, const int* __restrict__ cbase,
    int* __restrict__ mbase, int* __restrict__ mfront, int NBm, int E)
{
    int b = blockIdx.x, t = threadIdx.x;
    int m = (b << 6) + t;               // MPC == 64
    int v = (m < NBm) ? mcnt[m] : 0;
    int incl = v;
#pragma unroll
    for (int off = 1; off < 64; off <<= 1) {
        int x = __shfl_up(incl, off, 64);
        if (t >= off) incl += x;
    }
    if (m < NBm) {
        int ex = cbase[b] + incl - v;
        mbase[m] = ex; mfront[m] = ex;
    }
    if (b == (int)gridDim.x - 1 && t == 63) mbase[NBm] = E;
}

// ---- pass B: coarse-sorted staging -> mid (128-row) buckets; windowed LDS ranking ----
__global__ __launch_bounds__(256) void split_mid(
    const int2* __restrict__ stg1, const int* __restrict__ cbase_g,
    int* __restrict__ mfront, int2* __restrict__ stgm, int E, int NBc)
{
    __shared__ int cb[258];
    __shared__ int wc[MWIN], wg[MWIN];
    int t = threadIdx.x;
    for (int i = t; i <= NBc; i += 256) cb[i] = cbase_g[i];
    for (int i = t; i < MWIN; i += 256) wc[i] = 0;
    __syncthreads();
    int base = blockIdx.x * TILE_E;
    int lo = 0, hi = NBc - 1;
    while (lo < hi) { int m = (lo + hi + 1) >> 1; if (cb[m] <= base) lo = m; else hi = m - 1; }
    int winm = lo * MPC;
    int mylf[8], myrank[8]; int2 myp[8];
#pragma unroll
    for (int k = 0; k < 8; k++) {
        int e = base + k * 256 + t;
        mylf[k] = -1;
        if (e < E) {
            int b = lo;
            while (cb[b + 1] <= e) b++;
            int2 cv = stg1[e];
            int m = (b << (CSHIFT - MSHIFT)) + (int)(((unsigned)cv.x >> 19) >> MSHIFT);
            int lf = m - winm;
            if (lf >= 0 && lf < MWIN) { mylf[k] = lf; myrank[k] = atomicAdd(&wc[lf], 1); myp[k] = cv; }
            else stgm[atomicAdd(&mfront[m], 1)] = cv;   // rare fallback
        }
    }
    __syncthreads();
    for (int i = t; i < MWIN; i += 256)
        if (wc[i] > 0) wg[i] = atomicAdd(&mfront[winm + i], wc[i]);
    __syncthreads();
#pragma unroll
    for (int k = 0; k < 8; k++)
        if (mylf[k] >= 0) stgm[wg[mylf[k]] + myrank[k]] = myp[k];
}

// ---- pass C: one block per mid bucket; LDS counting sort to exact CSR ----
__global__ __launch_bounds__(256) void csr_sort(
    const int2* __restrict__ stgm, const int* __restrict__ mbase,
    int* __restrict__ rowptr, int2* __restrict__ ecv, int N)
{
    __shared__ int2 buf[CAP];
    __shared__ int cnt[128], sc[128], front[128];
    int mb = blockIdx.x, t = threadIdx.x;
    int row0 = mb << MSHIFT;
    int nrows = N - row0; if (nrows > 128) nrows = 128;
    int s = mbase[mb], eend = mbase[mb + 1];
    if (t < 128) cnt[t] = 0;
    __syncthreads();
    for (int i = s + t; i < eend; i += 256)
        atomicAdd(&cnt[((unsigned)stgm[i].x >> 19) & 127], 1);
    __syncthreads();
    if (t < 128) sc[t] = cnt[t];
    __syncthreads();
    for (int off = 1; off < 128; off <<= 1) {
        int x = (t >= off && t < 128) ? sc[t - off] : 0;
        __syncthreads();
        if (t < 128) sc[t] += x;
        __syncthreads();
    }
    if (t < 128) front[t] = sc[t] - cnt[t];
    if (t < nrows) rowptr[row0 + t] = s + sc[t] - cnt[t];
    if (t == 0 && row0 + nrows == N) rowptr[N] = eend;
    __syncthreads();
    for (int i = s + t; i < eend; i += 256) {
        int2 cv = stgm[i];
        unsigned p = (unsigned)cv.x;
        int rl = ((int)(p >> 19)) & 127;
        int2 rec = make_int2((int)(p & 0x7FFFFu), cv.y);
        int l = atomicAdd(&front[rl], 1);
        if (l < CAP) buf[l] = rec;
        else ecv[s + l] = rec;               // overflow fallback (statistically never)
    }
    __syncthreads();
    int total = eend - s; if (total > CAP) total = CAP;
    for (int l = t; l < total; l += 256) ecv[s + l] = buf[l];
}

// ======================= batched (3-dim) compute kernels =======================

struct DArgs {
    const float *in0, *in1, *in2;
    const float *W0, *W1, *W2;
    const float *bb0, *bb1, *bb2;
    float *H0, *H1, *H2;
    half_t *Z0, *Z1, *Z2;
    int n0, n1, n2;
    int base1, base2;
};

// H[n,:] = act(in[n,:]) @ W[0:32,:] + b (stride HS); Z[n,:] = act(in[n,:]) @ W[32:64,:] (fp16, stride ZS)
template<int COUT, bool LRELU, int HS, int ZS>
__global__ __launch_bounds__(256) void dense_kernel(DArgs A)
{
    int bid = blockIdx.x;
    int d = (bid >= A.base1 ? 1 : 0) + (bid >= A.base2 ? 1 : 0);
    int bb = d == 0 ? 0 : (d == 1 ? A.base1 : A.base2);
    int nd = d == 0 ? A.n0 : (d == 1 ? A.n1 : A.n2);
    const float* in = d == 0 ? A.in0 : (d == 1 ? A.in1 : A.in2);
    const float* W  = d == 0 ? A.W0  : (d == 1 ? A.W1  : A.W2);
    const float* b  = d == 0 ? A.bb0 : (d == 1 ? A.bb1 : A.bb2);
    float* H        = d == 0 ? A.H0  : (d == 1 ? A.H1  : A.H2);
    half_t* Z       = d == 0 ? A.Z0  : (d == 1 ? A.Z1  : A.Z2);
    int n = (bid - bb) * 256 + threadIdx.x;
    if (n >= nd) return;
    const float* row = in + (size_t)n * 32;
    float xv[32];
#pragma unroll
    for (int f = 0; f < 32; f += 4) {
        float4 v = *(const float4*)(row + f);
        xv[f] = v.x; xv[f + 1] = v.y; xv[f + 2] = v.z; xv[f + 3] = v.w;
    }
    if (LRELU) {
#pragma unroll
        for (int f = 0; f < 32; f++) xv[f] = xv[f] > 0.f ? xv[f] : NEG_SLOPE * xv[f];
    }
    float acct[COUT], accb[COUT];
#pragma unroll
    for (int c = 0; c < COUT; c++) { acct[c] = b[c]; accb[c] = 0.f; }
#pragma unroll 4
    for (int f = 0; f < 32; f++) {
        float xf = xv[f];
#pragma unroll
        for (int c = 0; c < COUT; c++) {
            acct[c] = fmaf(xf, W[f * COUT + c], acct[c]);
            accb[c] = fmaf(xf, W[(32 + f) * COUT + c], accb[c]);
        }
    }
    float* hrow = H + (size_t)n * HS;
    half_t* zrow = Z + (size_t)n * ZS;
#pragma unroll
    for (int c = 0; c < COUT; c += 2)
        *(float2*)(hrow + c) = make_float2(acct[c], acct[c + 1]);
#pragma unroll
    for (int c = 0; c < COUT; c += 2) {
        half2_t h;
        h.x = (half_t)accb[c];
        h.y = (half_t)accb[c + 1];
        *(half2_t*)(zrow + c) = h;
    }
}

struct GArgs {
    const int *rp0, *rp1, *rp2;
    const half_t *Z0, *Z1, *Z2;
    float *H0, *H1, *H2;
    int n0, n1, n2;
    int base1, base2;
};

// CSR gather, 2 interleaved row-chains x 2-edge unroll (4 Z-loads in flight / thread)
__global__ __launch_bounds__(256) void gather32(GArgs A, const int2* __restrict__ ecv)
{
    int bid = blockIdx.x;
    int d = (bid >= A.base1 ? 1 : 0) + (bid >= A.base2 ? 1 : 0);
    int bb = d == 0 ? 0 : (d == 1 ? A.base1 : A.base2);
    int nd = d == 0 ? A.n0 : (d == 1 ? A.n1 : A.n2);
    const int* rowptr = d == 0 ? A.rp0 : (d == 1 ? A.rp1 : A.rp2);
    const half_t* Z   = d == 0 ? A.Z0  : (d == 1 ? A.Z1  : A.Z2);
    float* H          = d == 0 ? A.H0  : (d == 1 ? A.H1  : A.H2);
    int tid = (bid - bb) * 256 + threadIdx.x;
    int pr = tid >> 3, lane = tid & 7;
    int r0 = pr * 2, r1 = r0 + 1;
    if (r0 >= nd) return;
    int s0 = rowptr[r0], e0 = rowptr[r0 + 1];
    int s1 = 0, e1 = 0;
    if (r1 < nd) { s1 = rowptr[r1]; e1 = rowptr[r1 + 1]; }
    float ax0 = 0.f, ay0 = 0.f, az0 = 0.f, aw0 = 0.f;
    float ax1 = 0.f, ay1 = 0.f, az1 = 0.f, aw1 = 0.f;
    int i0 = s0, i1 = s1;
    // 2-edge unrolled main loop: 4 independent ecv loads -> 4 independent Z loads
    while (i0 + 2 <= e0 && i1 + 2 <= e1) {
        int2 c0a = ecv[i0]; int2 c0b = ecv[i0 + 1];
        int2 c1a = ecv[i1]; int2 c1b = ecv[i1 + 1];
        half4_t z0a = *(const half4_t*)(Z + (size_t)c0a.x * 32 + lane * 4);
        half4_t z0b = *(const half4_t*)(Z + (size_t)c0b.x * 32 + lane * 4);
        half4_t z1a = *(const half4_t*)(Z + (size_t)c1a.x * 32 + lane * 4);
        half4_t z1b = *(const half4_t*)(Z + (size_t)c1b.x * 32 + lane * 4);
        float v0a = __int_as_float(c0a.y), v0b = __int_as_float(c0b.y);
        float v1a = __int_as_float(c1a.y), v1b = __int_as_float(c1b.y);
        ax0 = fmaf(v0a, (float)z0a.x, ax0); ay0 = fmaf(v0a, (float)z0a.y, ay0);
        az0 = fmaf(v0a, (float)z0a.z, az0); aw0 = fmaf(v0a, (float)z0a.w, aw0);
        ax0 = fmaf(v0b, (float)z0b.x, ax0); ay0 = fmaf(v0b, (float)z0b.y, ay0);
        az0 = fmaf(v0b, (float)z0b.z, az0); aw0 = fmaf(v0b, (float)z0b.w, aw0);
        ax1 = fmaf(v1a, (float)z1a.x, ax1); ay1 = fmaf(v1a, (float)z1a.y, ay1);
        az1 = fmaf(v1a, (float)z1a.z, az1); aw1 = fmaf(v1a, (float)z1a.w, aw1);
        ax1 = fmaf(v1b, (float)z1b.x, ax1); ay1 = fmaf(v1b, (float)z1b.y, ay1);
        az1 = fmaf(v1b, (float)z1b.z, az1); aw1 = fmaf(v1b, (float)z1b.w, aw1);
        i0 += 2; i1 += 2;
    }
    while (i0 < e0 && i1 < e1) {
        int2 c0 = ecv[i0]; int2 c1 = ecv[i1];
        half4_t z0 = *(const half4_t*)(Z + (size_t)c0.x * 32 + lane * 4);
        half4_t z1 = *(const half4_t*)(Z + (size_t)c1.x * 32 + lane * 4);
        float v0 = __int_as_float(c0.y), v1 = __int_as_float(c1.y);
        ax0 = fmaf(v0, (float)z0.x, ax0); ay0 = fmaf(v0, (float)z0.y, ay0);
        az0 = fmaf(v0, (float)z0.z, az0); aw0 = fmaf(v0, (float)z0.w, aw0);
        ax1 = fmaf(v1, (float)z1.x, ax1); ay1 = fmaf(v1, (float)z1.y, ay1);
        az1 = fmaf(v1, (float)z1.z, az1); aw1 = fmaf(v1, (float)z1.w, aw1);
        i0++; i1++;
    }
    for (; i0 + 2 <= e0; i0 += 2) {
        int2 c0a = ecv[i0]; int2 c0b = ecv[i0 + 1];
        half4_t z0a = *(const half4_t*)(Z + (size_t)c0a.x * 32 + lane * 4);
        half4_t z0b = *(const half4_t*)(Z + (size_t)c0b.x * 32 + lane * 4);
        float v0a = __int_as_float(c0a.y), v0b = __int_as_float(c0b.y);
        ax0 = fmaf(v0a, (float)z0a.x, ax0); ay0 = fmaf(v0a, (float)z0a.y, ay0);
        az0 = fmaf(v0a, (float)z0a.z, az0); aw0 = fmaf(v0a, (float)z0a.w, aw0);
        ax0 = fmaf(v0b, (float)z0b.x, ax0); ay0 = fmaf(v0b, (float)z0b.y, ay0);
        az0 = fmaf(v0b, (float)z0b.z, az0); aw0 = fmaf(v0b, (float)z0b.w, aw0);
    }
    for (; i0 < e0; i0++) {
        int2 c0 = ecv[i0];
        half4_t z0 = *(const half4_t*)(Z + (size_t)c0.x * 32 + lane * 4);
        float v0 = __int_as_float(c0.y);
        ax0 = fmaf(v0, (float)z0.x, ax0); ay0 = fmaf(v0, (float)z0.y, ay0);
        az0 = fmaf(v0, (float)z0.z, az0); aw0 = fmaf(v0, (float)z0.w, aw0);
    }
    for (; i1 + 2 <= e1; i1 += 2) {
        int2 c1a = ecv[i1]; int2 c1b = ecv[i1 + 1];
        half4_t z1a = *(const half4_t*)(Z + (size_t)c1a.x * 32 + lane * 4);
        half4_t z1b = *(const half4_t*)(Z + (size_t)c1b.x * 32 + lane * 4);
        float v1a = __int_as_float(c1a.y), v1b = __int_as_float(c1b.y);
        ax1 = fmaf(v1a, (float)z1a.x, ax1); ay1 = fmaf(v1a, (float)z1a.y, ay1);
        az1 = fmaf(v1a, (float)z1a.z, az1); aw1 = fmaf(v1a, (float)z1a.w, aw1);
        ax1 = fmaf(v1b, (float)z1b.x, ax1); ay1 = fmaf(v1b, (float)z1b.y, ay1);
        az1 = fmaf(v1b, (float)z1b.z, az1); aw1 = fmaf(v1b, (float)z1b.w, aw1);
    }
    for (; i1 < e1; i1++) {
        int2 c1 = ecv[i1];
        half4_t z1 = *(const half4_t*)(Z + (size_t)c1.x * 32 + lane * 4);
        float v1 = __int_as_float(c1.y);
        ax1 = fmaf(v1, (float)z1.x, ax1); ay1 = fmaf(v1, (float)z1.y, ay1);
        az1 = fmaf(v1, (float)z1.z, az1); aw1 = fmaf(v1, (float)z1.w, aw1);
    }
    float4* hp0 = (float4*)(H + (size_t)r0 * 32 + lane * 4);
    float4 h0 = *hp0;
    h0.x += ax0; h0.y += ay0; h0.z += az0; h0.w += aw0;
    *hp0 = h0;
    if (r1 < nd) {
        float4* hp1 = (float4*)(H + (size_t)r1 * 32 + lane * 4);
        float4 h1 = *hp1;
        h1.x += ax1; h1.y += ay1; h1.z += az1; h1.w += aw1;
        *hp1 = h1;
    }
}

// C=10 final gather: Z packed stride 16 halfs, H packed stride 16 floats, RMW; 2-edge unroll
__global__ __launch_bounds__(256) void gather10(GArgs A, const int2* __restrict__ ecv)
{
    int bid = blockIdx.x;
    int d = (bid >= A.base1 ? 1 : 0) + (bid >= A.base2 ? 1 : 0);
    int bb = d == 0 ? 0 : (d == 1 ? A.base1 : A.base2);
    int nd = d == 0 ? A.n0 : (d == 1 ? A.n1 : A.n2);
    const int* rowptr = d == 0 ? A.rp0 : (d == 1 ? A.rp1 : A.rp2);
    const half_t* Z   = d == 0 ? A.Z0  : (d == 1 ? A.Z1  : A.Z2);
    float* H          = d == 0 ? A.H0  : (d == 1 ? A.H1  : A.H2);
    int tid = (bid - bb) * 256 + threadIdx.x;
    int pr = tid >> 3, lane = tid & 7;
    int r0 = pr * 2, r1 = r0 + 1;
    if (r0 >= nd || lane >= 5) return;
    int s0 = rowptr[r0], e0 = rowptr[r0 + 1];
    int s1 = 0, e1 = 0;
    if (r1 < nd) { s1 = rowptr[r1]; e1 = rowptr[r1 + 1]; }
    float ax0 = 0.f, ay0 = 0.f, ax1 = 0.f, ay1 = 0.f;
    int i0 = s0, i1 = s1;
    while (i0 + 2 <= e0 && i1 + 2 <= e1) {
        int2 c0a = ecv[i0]; int2 c0b = ecv[i0 + 1];
        int2 c1a = ecv[i1]; int2 c1b = ecv[i1 + 1];
        half2_t z0a = *(const half2_t*)(Z + (size_t)c0a.x * 16 + lane * 2);
        half2_t z0b = *(const half2_t*)(Z + (size_t)c0b.x * 16 + lane * 2);
        half2_t z1a = *(const half2_t*)(Z + (size_t)c1a.x * 16 + lane * 2);
        half2_t z1b = *(const half2_t*)(Z + (size_t)c1b.x * 16 + lane * 2);
        float v0a = __int_as_float(c0a.y), v0b = __int_as_float(c0b.y);
        float v1a = __int_as_float(c1a.y), v1b = __int_as_float(c1b.y);
        ax0 = fmaf(v0a, (float)z0a.x, ax0); ay0 = fmaf(v0a, (float)z0a.y, ay0);
        ax0 = fmaf(v0b, (float)z0b.x, ax0); ay0 = fmaf(v0b, (float)z0b.y, ay0);
        ax1 = fmaf(v1a, (float)z1a.x, ax1); ay1 = fmaf(v1a, (float)z1a.y, ay1);
        ax1 = fmaf(v1b, (float)z1b.x, ax1); ay1 = fmaf(v1b, (float)z1b.y, ay1);
        i0 += 2; i1 += 2;
    }
    while (i0 < e0 && i1 < e1) {
        int2 c0 = ecv[i0]; int2 c1 = ecv[i1];
        half2_t z0 = *(const half2_t*)(Z + (size_t)c0.x * 16 + lane * 2);
        half2_t z1 = *(const half2_t*)(Z + (size_t)c1.x * 16 + lane * 2);
        float v0 = __int_as_float(c0.y), v1 = __int_as_float(c1.y);
        ax0 = fmaf(v0, (float)z0.x, ax0); ay0 = fmaf(v0, (float)z0.y, ay0);
        ax1 = fmaf(v1, (float)z1.x, ax1); ay1 = fmaf(v1, (float)z1.y, ay1);
        i0++; i1++;
    }
    for (; i0 + 2 <= e0; i0 += 2) {
        int2 c0a = ecv[i0]; int2 c0b = ecv[i0 + 1];
        half2_t z0a = *(const half2_t*)(Z + (size_t)c0a.x * 16 + lane * 2);
        half2_t z0b = *(const half2_t*)(Z + (size_t)c0b.x * 16 + lane * 2);
        float v0a = __int_as_float(c0a.y), v0b = __int_as_float(c0b.y);
        ax0 = fmaf(v0a, (float)z0a.x, ax0); ay0 = fmaf(v0a, (float)z0a.y, ay0);
        ax0 = fmaf(v0b, (float)z0b.x, ax0); ay0 = fmaf(v0b, (float)z0b.y, ay0);
    }
    for (; i0 < e0; i0++) {
        int2 c0 = ecv[i0];
        half2_t z0 = *(const half2_t*)(Z + (size_t)c0.x * 16 + lane * 2);
        float v0 = __int_as_float(c0.y);
        ax0 = fmaf(v0, (float)z0.x, ax0); ay0 = fmaf(v0, (float)z0.y, ay0);
    }
    for (; i1 + 2 <= e1; i1 += 2) {
        int2 c1a = ecv[i1]; int2 c1b = ecv[i1 + 1];
        half2_t z1a = *(const half2_t*)(Z + (size_t)c1a.x * 16 + lane * 2);
        half2_t z1b = *(const half2_t*)(Z + (size_t)c1b.x * 16 + lane * 2);
        float v1a = __int_as_float(c1a.y), v1b = __int_as_float(c1b.y);
        ax1 = fmaf(v1a, (float)z1a.x, ax1); ay1 = fmaf(v1a, (float)z1a.y, ay1);
        ax1 = fmaf(v1b, (float)z1b.x, ax1); ay1 = fmaf(v1b, (float)z1b.y, ay1);
    }
    for (; i1 < e1; i1++) {
        int2 c1 = ecv[i1];
        half2_t z1 = *(const half2_t*)(Z + (size_t)c1.x * 16 + lane * 2);
        float v1 = __int_as_float(c1.y);
        ax1 = fmaf(v1, (float)z1.x, ax1); ay1 = fmaf(v1, (float)z1.y, ay1);
    }
    float* hp0 = H + (size_t)r0 * 16 + lane * 2;
    hp0[0] += ax0; hp0[1] += ay0;
    if (r1 < nd) {
        float* hp1 = H + (size_t)r1 * 16 + lane * 2;
        hp1[0] += ax1; hp1[1] += ay1;
    }
}

struct PArgs {
    const float *H0, *H1, *H2;
    const int *bt0, *bt1, *bt2;
    int n0, n1, n2;
};

// 3*G blocks: block -> (dim, graph); batch sorted -> binary search, no atomics; H stride 16
__global__ __launch_bounds__(256) void pool_graph(PArgs A, float* __restrict__ pool, int G)
{
    int bid = blockIdx.x;
    int d = (bid >= G ? 1 : 0) + (bid >= 2 * G ? 1 : 0);
    int g = bid - d * G;
    const float* H = d == 0 ? A.H0 : (d == 1 ? A.H1 : A.H2);
    const int* batch = d == 0 ? A.bt0 : (d == 1 ? A.bt1 : A.bt2);
    int N = d == 0 ? A.n0 : (d == 1 ? A.n1 : A.n2);
    int lo = 0, hi = N;
    while (lo < hi) { int mid = (lo + hi) >> 1; if (batch[mid] < g) lo = mid + 1; else hi = mid; }
    int start = lo;
    lo = start; hi = N;
    while (lo < hi) { int mid = (lo + hi) >> 1; if (batch[mid] < g + 1) lo = mid + 1; else hi = mid; }
    int end = lo;
    int t = threadIdx.x, f = t & 15, chain = t >> 4;
    __shared__ float sd[256];
    float acc = 0.f;
    if (f < 10) {
        for (int i = start + chain; i < end; i += 16) acc += H[(size_t)i * 16 + f];
    }
    sd[t] = acc; __syncthreads();
    if (chain == 0 && f < 10) {
        float s = 0.f;
#pragma unroll
        for (int k = 0; k < 16; k++) s += sd[k * 16 + f];
        int c = end - start;
        float inv = 1.f / (float)(c > 1 ? c : 1);
        pool[(size_t)g * 30 + d * 10 + f] = s * inv;
    }
}

__global__ __launch_bounds__(256) void final_kernel(
    const float* __restrict__ pool, const float* __restrict__ Wf,
    const float* __restrict__ bfv, float* __restrict__ out, int G)
{
    int g = blockIdx.x * 256 + threadIdx.x;
    if (g >= G) return;
    float m[30];
#pragma unroll
    for (int j = 0; j < 30; j++) m[j] = pool[(size_t)g * 30 + j];
    float lg[10];
#pragma unroll
    for (int o = 0; o < 10; o++) {
        float a = bfv[o];
#pragma unroll
        for (int j = 0; j < 30; j++) a = fmaf(m[j], Wf[j * 10 + o], a);
        lg[o] = a;
    }
    float mx = lg[0];
#pragma unroll
    for (int o = 1; o < 10; o++) mx = fmaxf(mx, lg[o]);
    float s = 0.f;
#pragma unroll
    for (int o = 0; o < 10; o++) { lg[o] = __expf(lg[o] - mx); s += lg[o]; }
    float invs = 1.f / s;
#pragma unroll
    for (int o = 0; o < 10; o++) out[(size_t)g * 10 + o] = lg[o] * invs;
}

extern "C" void kernel_launch(void* const* d_in, const int* in_sizes, int n_in,
                              void* d_out, int out_size, void* d_ws, size_t ws_size,
                              hipStream_t stream)
{
    (void)n_in;
    const float* x[3]    = {(const float*)d_in[0], (const float*)d_in[1], (const float*)d_in[2]};
    const float* vals[3] = {(const float*)d_in[3], (const float*)d_in[4], (const float*)d_in[5]};
    const int* rows[3]   = {(const int*)d_in[6], (const int*)d_in[8], (const int*)d_in[10]};
    const int* cols[3]   = {(const int*)d_in[7], (const int*)d_in[9], (const int*)d_in[11]};
    const int* batch[3]  = {(const int*)d_in[12], (const int*)d_in[13], (const int*)d_in[14]};
    const float* W1[3] = {(const float*)d_in[16], (const float*)d_in[22], (const float*)d_in[28]};
    const float* b1[3] = {(const float*)d_in[17], (const float*)d_in[23], (const float*)d_in[29]};
    const float* W2[3] = {(const float*)d_in[18], (const float*)d_in[24], (const float*)d_in[30]};
    const float* b2[3] = {(const float*)d_in[19], (const float*)d_in[25], (const float*)d_in[31]};
    const float* W3[3] = {(const float*)d_in[20], (const float*)d_in[26], (const float*)d_in[32]};
    const float* b3[3] = {(const float*)d_in[21], (const float*)d_in[27], (const float*)d_in[33]};
    const float* Wf  = (const float*)d_in[34];
    const float* bfv = (const float*)d_in[35];
    float* out = (float*)d_out;

    int N[3] = {in_sizes[0] / 32, in_sizes[1] / 32, in_sizes[2] / 32};
    int E[3] = {in_sizes[3], in_sizes[4], in_sizes[5]};
    int G = out_size / 10;
    int maxN = N[0]; if (N[1] > maxN) maxN = N[1]; if (N[2] > maxN) maxN = N[2];
    int maxE = E[0]; if (E[1] > maxE) maxE = E[1]; if (E[2] > maxE) maxE = E[2];

    // union (bucket-aligned) row offsets; cols stay LOCAL everywhere
    int o1 = cdiv(N[0], RALIGN) * RALIGN;
    int o2 = o1 + cdiv(N[1], RALIGN) * RALIGN;
    int NU = o2 + N[2];
    long long EU = (long long)E[0] + E[1] + E[2];
    int NBcU = cdiv(NU, RALIGN);
    int NBmU = cdiv(NU, 1 << MSHIFT);
    size_t sumN = (size_t)N[0] + N[1] + N[2];
    size_t pN[3] = {0, (size_t)N[0], (size_t)N[0] + N[1]};
    int offsU[3] = {0, o1, o2};

    char* base = (char*)d_ws;

    // ---- batched layout ----
    // [0, regC): build stg1[EU] + stgm[EU] / compute bufA3(sumN*128B) + bufZ3(sumN*64B)
    size_t regC = al16((size_t)2 * EU * 8 > sumN * 192 ? (size_t)2 * EU * 8 : sumN * 192);
    size_t off_z3  = regC;                                  // Z3p packed: sumN*32 B
    size_t off_ecv = al16(off_z3 + sumN * 32);
    size_t off_rp  = off_ecv + (size_t)EU * 8;
    size_t off_cnt = al16(off_rp + ((size_t)NU + 1) * 4);
    size_t cnt_ints = (size_t)3 * NBmU + 1 + 256 + 258 + 256;
    size_t off_pool = al16(off_cnt + cnt_ints * 4);
    size_t need = off_pool + (size_t)G * 30 * 4;
    bool batched = (need <= ws_size);

    if (batched) {
        int2* stg1 = (int2*)base;
        int2* stgm = (int2*)(base + (size_t)EU * 8);
        float* bufA3 = (float*)base;
        half_t* bufZ3 = (half_t*)(base + sumN * 128);
        float* H3p3 = (float*)(base + sumN * 128);          // replaces Z1/Z2 region at layer 3
        half_t* Z3p3 = (half_t*)(base + off_z3);
        int2* ecv = (int2*)(base + off_ecv);
        int* rowptrU = (int*)(base + off_rp);
        int* mcnt = (int*)(base + off_cnt);
        int* mbase = mcnt + NBmU;
        int* mfront = mbase + NBmU + 1;
        int* ccnt = mfront + NBmU;
        int* cbase = ccnt + 256;
        int* cfront = cbase + 258;
        float* pool = (float*)(base + off_pool);

        // ---- ONE union build for all 3 dims ----
        Src3 S;
        S.r0 = rows[0]; S.c0 = cols[0]; S.v0 = vals[0];
        S.r1 = rows[1]; S.c1 = cols[1]; S.v1 = vals[1];
        S.r2 = rows[2]; S.c2 = cols[2]; S.v2 = vals[2];
        S.e1 = E[0]; S.e2 = E[0] + E[1]; S.etot = (int)EU;
        S.o1 = o1; S.o2 = o2;
        int ntileU = cdiv(EU, TILE_E);
        int zlenU = 3 * NBmU + 257;     // mcnt + mbase + mfront + ccnt (contiguous)
        zero_i32<<<cdiv(zlenU, 256), 256, 0, stream>>>(mcnt, zlenU);
        hist_coarse<<<ntileU, 256, 0, stream>>>(S, ccnt);
        scan_coarse<<<1, 64, 0, stream>>>(ccnt, cbase, cfront, NBcU, (int)EU);
        split_coarse<<<ntileU, 256, 0, stream>>>(S, cfront, stg1);
        hist_mid<<<ntileU, 256, 0, stream>>>(stg1, cbase, mcnt, (int)EU, NBcU);
        scan_mid_par<<<NBcU, 64, 0, stream>>>(mcnt, cbase, mbase, mfront, NBmU, (int)EU);
        split_mid<<<ntileU, 256, 0, stream>>>(stg1, cbase, mfront, stgm, (int)EU, NBcU);
        csr_sort<<<NBmU, 256, 0, stream>>>(stgm, mbase, rowptrU, ecv, NU);

        // ---- per-layer batched compute across all 3 dims ----
        int nb[3], gb[3];
        for (int d = 0; d < 3; d++) {
            nb[d] = cdiv(N[d], 256);
            gb[d] = cdiv((long long)cdiv(N[d], 2) * 8, 256);
        }
        DArgs D;
        D.in0 = x[0]; D.in1 = x[1]; D.in2 = x[2];
        D.W0 = W1[0]; D.W1 = W1[1]; D.W2 = W1[2];
        D.bb0 = b1[0]; D.bb1 = b1[1]; D.bb2 = b1[2];
        D.H0 = bufA3 + pN[0] * 32; D.H1 = bufA3 + pN[1] * 32; D.H2 = bufA3 + pN[2] * 32;
        D.Z0 = bufZ3 + pN[0] * 32; D.Z1 = bufZ3 + pN[1] * 32; D.Z2 = bufZ3 + pN[2] * 32;
        D.n0 = N[0]; D.n1 = N[1]; D.n2 = N[2];
        D.base1 = nb[0]; D.base2 = nb[0] + nb[1];
        int nbsum = nb[0] + nb[1] + nb[2];

        GArgs Gg;
        Gg.rp0 = rowptrU + offsU[0]; Gg.rp1 = rowptrU + offsU[1]; Gg.rp2 = rowptrU + offsU[2];
        Gg.Z0 = D.Z0; Gg.Z1 = D.Z1; Gg.Z2 = D.Z2;
        Gg.H0 = D.H0; Gg.H1 = D.H1; Gg.H2 = D.H2;
        Gg.n0 = N[0]; Gg.n1 = N[1]; Gg.n2 = N[2];
        Gg.base1 = gb[0]; Gg.base2 = gb[0] + gb[1];
        int gbsum = gb[0] + gb[1] + gb[2];

        dense_kernel<32, false, 32, 32><<<nbsum, 256, 0, stream>>>(D);
        gather32<<<gbsum, 256, 0, stream>>>(Gg, ecv);
        D.in0 = D.H0; D.in1 = D.H1; D.in2 = D.H2;
        D.W0 = W2[0]; D.W1 = W2[1]; D.W2 = W2[2];
        D.bb0 = b2[0]; D.bb1 = b2[1]; D.bb2 = b2[2];
        dense_kernel<32, true, 32, 32><<<nbsum, 256, 0, stream>>>(D);
        gather32<<<gbsum, 256, 0, stream>>>(Gg, ecv);
        // layer 3: packed H (stride 16 f32, in old Z region) + packed Z (stride 16 half)
        DArgs D3 = D;
        D3.W0 = W3[0]; D3.W1 = W3[1]; D3.W2 = W3[2];
        D3.bb0 = b3[0]; D3.bb1 = b3[1]; D3.bb2 = b3[2];
        D3.H0 = H3p3 + pN[0] * 16; D3.H1 = H3p3 + pN[1] * 16; D3.H2 = H3p3 + pN[2] * 16;
        D3.Z0 = Z3p3 + pN[0] * 16; D3.Z1 = Z3p3 + pN[1] * 16; D3.Z2 = Z3p3 + pN[2] * 16;
        dense_kernel<10, true, 16, 16><<<nbsum, 256, 0, stream>>>(D3);
        GArgs G10 = Gg;
        G10.Z0 = D3.Z0; G10.Z1 = D3.Z1; G10.Z2 = D3.Z2;
        G10.H0 = D3.H0; G10.H1 = D3.H1; G10.H2 = D3.H2;
        gather10<<<gbsum, 256, 0, stream>>>(G10, ecv);
        PArgs P;
        P.H0 = D3.H0; P.H1 = D3.H1; P.H2 = D3.H2;
        P.bt0 = batch[0]; P.bt1 = batch[1]; P.bt2 = batch[2];
        P.n0 = N[0]; P.n1 = N[1]; P.n2 = N[2];
        pool_graph<<<3 * G, 256, 0, stream>>>(P, pool, G);
        final_kernel<<<cdiv(G, 256), 256, 0, stream>>>(pool, Wf, bfv, out, G);
    } else {
        // ---- fallback: per-dim build + compute (R5-equivalent layout), same kernels ----
        int maxNBm = cdiv(maxN, 1 << MSHIFT);
        float* bufA = (float*)base;
        half_t* bufZh = (half_t*)(base + (size_t)maxN * 128);
        float* H3p = (float*)(base + (size_t)maxN * 128);
        half_t* Z3p = (half_t*)(base + (size_t)maxN * 128 + (size_t)maxN * 64);
        float* pool = (float*)(base + (size_t)maxN * 256);
        int2* ecv = (int2*)(base + al16((size_t)maxN * 256 + (size_t)G * 30 * 4));
        int* rowptr = (int*)(ecv + maxE);
        int* mcnt = rowptr + (maxN + 1);
        int* mbase = mcnt + maxNBm;
        int* mfront = mbase + (maxNBm + 1);
        int* ccnt = mfront + maxNBm;
        int* cbase = ccnt + 256;
        int* cfront = cbase + 258;
        int2* stg1 = (int2*)bufA;
        int2* stgm = (int2*)(base + (size_t)maxN * 128);
        int zlen = 3 * maxNBm + 257;
        for (int d = 0; d < 3; d++) {
            int n = N[d], e = E[d];
            int NBc = cdiv(n, RALIGN);
            int NBm = cdiv(n, 1 << MSHIFT);
            int ntile = cdiv(e, TILE_E);
            int nb = cdiv(n, 256);
            int gbl = cdiv((long long)cdiv(n, 2) * 8, 256);
            Src3 S;
            S.r0 = rows[d]; S.c0 = cols[d]; S.v0 = vals[d];
            S.r1 = rows[d]; S.c1 = cols[d]; S.v1 = vals[d];
            S.r2 = rows[d]; S.c2 = cols[d]; S.v2 = vals[d];
            S.e1 = e; S.e2 = e; S.etot = e; S.o1 = 0; S.o2 = 0;
            zero_i32<<<cdiv(zlen, 256), 256, 0, stream>>>(mcnt, zlen);
            hist_coarse<<<ntile, 256, 0, stream>>>(S, ccnt);
            scan_coarse<<<1, 64, 0, stream>>>(ccnt, cbase, cfront, NBc, e);
            split_coarse<<<ntile, 256, 0, stream>>>(S, cfront, stg1);
            hist_mid<<<ntile, 256, 0, stream>>>(stg1, cbase, mcnt, e, NBc);
            scan_mid_par<<<NBc, 64, 0, stream>>>(mcnt, cbase, mbase, mfront, NBm, e);
            split_mid<<<ntile, 256, 0, stream>>>(stg1, cbase, mfront, stgm, e, NBc);
            csr_sort<<<NBm, 256, 0, stream>>>(stgm, mbase, rowptr, ecv, n);

            DArgs D;
            D.in0 = x[d]; D.in1 = x[d]; D.in2 = x[d];
            D.W0 = W1[d]; D.W1 = W1[d]; D.W2 = W1[d];
            D.bb0 = b1[d]; D.bb1 = b1[d]; D.bb2 = b1[d];
            D.H0 = bufA; D.H1 = bufA; D.H2 = bufA;
            D.Z0 = bufZh; D.Z1 = bufZh; D.Z2 = bufZh;
            D.n0 = n; D.n1 = n; D.n2 = n;
            D.base1 = nb; D.base2 = nb;
            GArgs Gg;
            Gg.rp0 = rowptr; Gg.rp1 = rowptr; Gg.rp2 = rowptr;
            Gg.Z0 = bufZh; Gg.Z1 = bufZh; Gg.Z2 = bufZh;
            Gg.H0 = bufA; Gg.H1 = bufA; Gg.H2 = bufA;
            Gg.n0 = n; Gg.n1 = n; Gg.n2 = n;
            Gg.base1 = gbl; Gg.base2 = gbl;
            dense_kernel<32, false, 32, 32><<<nb, 256, 0, stream>>>(D);
            gather32<<<gbl, 256, 0, stream>>>(Gg, ecv);
            D.in0 = bufA; D.in1 = bufA; D.in2 = bufA;
            D.W0 = W2[d]; D.W1 = W2[d]; D.W2 = W2[d];
            D.bb0 = b2[d]; D.bb1 = b2[d]; D.bb2 = b2[d];
            dense_kernel<32, true, 32, 32><<<nb, 256, 0, stream>>>(D);
            gather32<<<gbl, 256, 0, stream>>>(Gg, ecv);
            DArgs D3 = D;
            D3.W0 = W3[d]; D3.W1 = W3[d]; D3.W2 = W3[d];
            D3.bb0 = b3[d]; D3.bb1 = b3[d]; D3.bb2 = b3[d];
            D3.H0 = H3p; D3.H1 = H3p; D3.H2 = H3p;
            D3.Z0 = Z3p; D3.Z1 = Z3p; D3.Z2 = Z3p;
            dense_kernel<10, true, 16, 16><<<nb, 256, 0, stream>>>(D3);
            GArgs G10 = Gg;
            G10.Z0 = Z3p; G10.Z1 = Z3p; G10.Z2 = Z3p;
            G10.H0 = H3p; G10.H1 = H3p; G10.H2 = H3p;
            gather10<<<gbl, 256, 0, stream>>>(G10, ecv);
            PArgs P;
            P.H0 = H3p; P.H1 = H3p; P.H2 = H3p;
            P.bt0 = batch[d]; P.bt1 = batch[d]; P.bt2 = batch[d];
            P.n0 = n; P.n1 = n; P.n2 = n;
            // G-block launch => in-kernel d==0; offset pool base by d*10 so each dim
            // lands in its [g*30 + d*10 + f] slot
            pool_graph<<<G, 256, 0, stream>>>(P, pool + (size_t)d * 10, G);
        }
        final_kernel<<<cdiv(G, 256), 256, 0, stream>>>(pool, Wf, bfv, out, G);
    }
}

// Round 11
// 1092.112 us; speedup vs baseline: 1.4159x; 1.0116x over previous
//
#include <hip/hip_runtime.h>
#include <stdint.h>

#define NEG_SLOPE 0.01f
#define CSHIFT 13               // 8192 rows per coarse bucket
#define RALIGN (1 << CSHIFT)
#define MSHIFT 7                // 128 rows per mid bucket
#define MPC (1 << (CSHIFT - MSHIFT))   // 64 mids per coarse
#define MWIN 192                // window of mid-counters per split tile (straddle<=2 coarse)
#define CAP 4096                // max edges per mid bucket in csr_sort LDS
#define TILE_E 2048             // edges per split tile

typedef _Float16 half_t;
typedef _Float16 half2_t __attribute__((ext_vector_type(2)));
typedef _Float16 half4_t __attribute__((ext_vector_type(4)));

static inline int cdiv(long long a, long long b) { return (int)((a + b - 1) / b); }
static inline size_t al16(size_t x) { return (x + 15) & ~(size_t)15; }

// up to 3 edge sources concatenated: [0,e1) dim0 (+0), [e1,e2) dim1 (+o1), [e2,etot) dim2 (+o2)
struct Src3 {
    const int* r0; const int* c0; const float* v0;
    const int* r1; const int* c1; const float* v1;
    const int* r2; const int* c2; const float* v2;
    int e1, e2, etot;
    int o1, o2;
};

__device__ __forceinline__ int fetch_row(const Src3& S, int e) {
    if (e < S.e1) return S.r0[e];
    if (e < S.e2) return S.r1[e - S.e1] + S.o1;
    return S.r2[e - S.e2] + S.o2;
}
__device__ __forceinline__ void fetch_edge(const Src3& S, int e, int& r, unsigned& c, float& v) {
    if (e < S.e1) { r = S.r0[e]; c = (unsigned)S.c0[e]; v = S.v0[e]; }
    else if (e < S.e2) { int i = e - S.e1; r = S.r1[i] + S.o1; c = (unsigned)S.c1[i]; v = S.v1[i]; }
    else { int i = e - S.e2; r = S.r2[i] + S.o2; c = (unsigned)S.c2[i]; v = S.v2[i]; }
}

__global__ __launch_bounds__(256) void zero_i32(int* __restrict__ p, int n) {
    int i = blockIdx.x * 256 + threadIdx.x;
    if (i < n) p[i] = 0;
}

// ---- coarse histogram: LDS counters (<=256 buckets), one merge atomic per (block,bucket) ----
__global__ __launch_bounds__(256) void hist_coarse(Src3 S, int* __restrict__ ccnt) {
    __shared__ int cnt[256];
    int t = threadIdx.x;
    cnt[t] = 0;
    __syncthreads();
    int base = blockIdx.x * TILE_E;
#pragma unroll
    for (int k = 0; k < TILE_E / 256; k++) {
        int e = base + k * 256 + t;
        if (e < S.etot) atomicAdd(&cnt[fetch_row(S, e) >> CSHIFT], 1);
    }
    __syncthreads();
    if (cnt[t] > 0) atomicAdd(&ccnt[t], cnt[t]);
}

__global__ void scan_coarse(const int* __restrict__ ccnt, int* __restrict__ cbase,
                            int* __restrict__ cfront, int NBc, int E) {
    if (threadIdx.x == 0 && blockIdx.x == 0) {
        int run = 0;
        for (int b = 0; b < NBc; b++) { cbase[b] = run; cfront[b] = run; run += ccnt[b]; }
        cbase[NBc] = E;
    }
}

// ---- pass A: LDS multisplit into coarse buckets; dense chunk writes ----
// record: ( (row & 8191) << 19 | col_local , val )
__global__ __launch_bounds__(256) void split_coarse(
    Src3 S, int* __restrict__ cfront, int2* __restrict__ stg1)
{
    __shared__ int cnt[256], gb[256];
    int t = threadIdx.x;
    cnt[t] = 0;
    __syncthreads();
    int base = blockIdx.x * TILE_E;
    int myb[8], myrank[8]; int2 mycv[8];
#pragma unroll
    for (int k = 0; k < 8; k++) {
        int e = base + k * 256 + t;
        myb[k] = -1;
        if (e < S.etot) {
            int r; unsigned c; float v;
            fetch_edge(S, e, r, c, v);
            int b = r >> CSHIFT;
            mycv[k] = make_int2((int)(((unsigned)(r & (RALIGN - 1)) << 19) | c),
                                __float_as_int(v));
            myb[k] = b;
            myrank[k] = atomicAdd(&cnt[b], 1);
        }
    }
    __syncthreads();
    if (cnt[t] > 0) gb[t] = atomicAdd(&cfront[t], cnt[t]);
    __syncthreads();
#pragma unroll
    for (int k = 0; k < 8; k++)
        if (myb[k] >= 0) stg1[gb[myb[k]] + myrank[k]] = mycv[k];
}

// ---- mid histogram from coarse-sorted staging (windowed LDS counters) ----
__global__ __launch_bounds__(256) void hist_mid(
    const int2* __restrict__ stg1, const int* __restrict__ cbase_g,
    int* __restrict__ mcnt, int E, int NBc)
{
    __shared__ int cb[258];
    __shared__ int wc[MWIN];
    int t = threadIdx.x;
    for (int i = t; i <= NBc; i += 256) cb[i] = cbase_g[i];
    for (int i = t; i < MWIN; i += 256) wc[i] = 0;
    __syncthreads();
    int base = blockIdx.x * TILE_E;
    int lo = 0, hi = NBc - 1;
    while (lo < hi) { int m = (lo + hi + 1) >> 1; if (cb[m] <= base) lo = m; else hi = m - 1; }
    int winm = lo * MPC;
#pragma unroll
    for (int k = 0; k < 8; k++) {
        int e = base + k * 256 + t;
        if (e < E) {
            int b = lo;
            while (cb[b + 1] <= e) b++;
            int m = b * MPC + (int)(((unsigned)stg1[e].x >> 19) >> MSHIFT);
            int lf = m - winm;
            if (lf >= 0 && lf < MWIN) atomicAdd(&wc[lf], 1);
            else atomicAdd(&mcnt[m], 1);    // rare fallback
        }
    }
    __syncthreads();
    for (int i = t; i < MWIN; i += 256)
        if (wc[i] > 0) atomicAdd(&mcnt[winm + i], wc[i]);
}

// ---- parallel scan over mid buckets: one wave per coarse bucket (64 mids each);
//      global carry is cbase[b], so no cross-block dependency ----
__global__ __launch_bounds__(64) void scan_mid_par(
    const int* __restrict__ mcnt, const int* __restrict__ cbase,
    int* __restrict__ mbase, int* __restrict__ mfront, int NBm, int E)
{
    int b = blockIdx.x, t = threadIdx.x;
    int m = (b << 6) + t;               // MPC == 64
    int v = (m < NBm) ? mcnt[m] : 0;
    int incl = v;
#pragma unroll
    for (int off = 1; off < 64; off <<= 1) {
        int x = __shfl_up(incl, off, 64);
        if (t >= off) incl += x;
    }
    if (m < NBm) {
        int ex = cbase[b] + incl - v;
        mbase[m] = ex; mfront[m] = ex;
    }
    if (b == (int)gridDim.x - 1 && t == 63) mbase[NBm] = E;
}

// ---- pass B: coarse-sorted staging -> mid (128-row) buckets; windowed LDS ranking ----
__global__ __launch_bounds__(256) void split_mid(
    const int2* __restrict__ stg1, const int* __restrict__ cbase_g,
    int* __restrict__ mfront, int2* __restrict__ stgm, int E, int NBc)
{
    __shared__ int cb[258];
    __shared__ int wc[MWIN], wg[MWIN];
    int t = threadIdx.x;
    for (int i = t; i <= NBc; i += 256) cb[i] = cbase_g[i];
    for (int i = t; i < MWIN; i += 256) wc[i] = 0;
    __syncthreads();
    int base = blockIdx.x * TILE_E;
    int lo = 0, hi = NBc - 1;
    while (lo < hi) { int m = (lo + hi + 1) >> 1; if (cb[m] <= base) lo = m; else hi = m - 1; }
    int winm = lo * MPC;
    int mylf[8], myrank[8]; int2 myp[8];
#pragma unroll
    for (int k = 0; k < 8; k++) {
        int e = base + k * 256 + t;
        mylf[k] = -1;
        if (e < E) {
            int b = lo;
            while (cb[b + 1] <= e) b++;
            int2 cv = stg1[e];
            int m = (b << (CSHIFT - MSHIFT)) + (int)(((unsigned)cv.x >> 19) >> MSHIFT);
            int lf = m - winm;
            if (lf >= 0 && lf < MWIN) { mylf[k] = lf; myrank[k] = atomicAdd(&wc[lf], 1); myp[k] = cv; }
            else stgm[atomicAdd(&mfront[m], 1)] = cv;   // rare fallback
        }
    }
    __syncthreads();
    for (int i = t; i < MWIN; i += 256)
        if (wc[i] > 0) wg[i] = atomicAdd(&mfront[winm + i], wc[i]);
    __syncthreads();
#pragma unroll
    for (int k = 0; k < 8; k++)
        if (mylf[k] >= 0) stgm[wg[mylf[k]] + myrank[k]] = myp[k];
}

// ---- pass C: one block per mid bucket; LDS counting sort to exact CSR ----
__global__ __launch_bounds__(256) void csr_sort(
    const int2* __restrict__ stgm, const int* __restrict__ mbase,
    int* __restrict__ rowptr, int2* __restrict__ ecv, int N)
{
    __shared__ int2 buf[CAP];
    __shared__ int cnt[128], sc[128], front[128];
    int mb = blockIdx.x, t = threadIdx.x;
    int row0 = mb << MSHIFT;
    int nrows = N - row0; if (nrows > 128) nrows = 128;
    int s = mbase[mb], eend = mbase[mb + 1];
    if (t < 128) cnt[t] = 0;
    __syncthreads();
    for (int i = s + t; i < eend; i += 256)
        atomicAdd(&cnt[((unsigned)stgm[i].x >> 19) & 127], 1);
    __syncthreads();
    if (t < 128) sc[t] = cnt[t];
    __syncthreads();
    for (int off = 1; off < 128; off <<= 1) {
        int x = (t >= off && t < 128) ? sc[t - off] : 0;
        __syncthreads();
        if (t < 128) sc[t] += x;
        __syncthreads();
    }
    if (t < 128) front[t] = sc[t] - cnt[t];
    if (t < nrows) rowptr[row0 + t] = s + sc[t] - cnt[t];
    if (t == 0 && row0 + nrows == N) rowptr[N] = eend;
    __syncthreads();
    for (int i = s + t; i < eend; i += 256) {
        int2 cv = stgm[i];
        unsigned p = (unsigned)cv.x;
        int rl = ((int)(p >> 19)) & 127;
        int2 rec = make_int2((int)(p & 0x7FFFFu), cv.y);
        int l = atomicAdd(&front[rl], 1);
        if (l < CAP) buf[l] = rec;
        else ecv[s + l] = rec;               // overflow fallback (statistically never)
    }
    __syncthreads();
    int total = eend - s; if (total > CAP) total = CAP;
    for (int l = t; l < total; l += 256) ecv[s + l] = buf[l];
}

// ======================= batched (3-dim) compute kernels =======================

struct DArgs {
    const float *in0, *in1, *in2;
    const float *W0, *W1, *W2;
    const float *bb0, *bb1, *bb2;
    float *H0, *H1, *H2;
    half_t *Z0, *Z1, *Z2;
    int n0, n1, n2;
    int base1, base2;
};

// H[n,:] = act(in[n,:]) @ W[0:32,:] + b (stride HS); Z[n,:] = act(in[n,:]) @ W[32:64,:] (fp16, stride ZS)
template<int COUT, bool LRELU, int HS, int ZS>
__global__ __launch_bounds__(256) void dense_kernel(DArgs A)
{
    int bid = blockIdx.x;
    int d = (bid >= A.base1 ? 1 : 0) + (bid >= A.base2 ? 1 : 0);
    int bb = d == 0 ? 0 : (d == 1 ? A.base1 : A.base2);
    int nd = d == 0 ? A.n0 : (d == 1 ? A.n1 : A.n2);
    const float* in = d == 0 ? A.in0 : (d == 1 ? A.in1 : A.in2);
    const float* W  = d == 0 ? A.W0  : (d == 1 ? A.W1  : A.W2);
    const float* b  = d == 0 ? A.bb0 : (d == 1 ? A.bb1 : A.bb2);
    float* H        = d == 0 ? A.H0  : (d == 1 ? A.H1  : A.H2);
    half_t* Z       = d == 0 ? A.Z0  : (d == 1 ? A.Z1  : A.Z2);
    int n = (bid - bb) * 256 + threadIdx.x;
    if (n >= nd) return;
    const float* row = in + (size_t)n * 32;
    float xv[32];
#pragma unroll
    for (int f = 0; f < 32; f += 4) {
        float4 v = *(const float4*)(row + f);
        xv[f] = v.x; xv[f + 1] = v.y; xv[f + 2] = v.z; xv[f + 3] = v.w;
    }
    if (LRELU) {
#pragma unroll
        for (int f = 0; f < 32; f++) xv[f] = xv[f] > 0.f ? xv[f] : NEG_SLOPE * xv[f];
    }
    float acct[COUT], accb[COUT];
#pragma unroll
    for (int c = 0; c < COUT; c++) { acct[c] = b[c]; accb[c] = 0.f; }
#pragma unroll 4
    for (int f = 0; f < 32; f++) {
        float xf = xv[f];
#pragma unroll
        for (int c = 0; c < COUT; c++) {
            acct[c] = fmaf(xf, W[f * COUT + c], acct[c]);
            accb[c] = fmaf(xf, W[(32 + f) * COUT + c], accb[c]);
        }
    }
    float* hrow = H + (size_t)n * HS;
    half_t* zrow = Z + (size_t)n * ZS;
#pragma unroll
    for (int c = 0; c < COUT; c += 2)
        *(float2*)(hrow + c) = make_float2(acct[c], acct[c + 1]);
#pragma unroll
    for (int c = 0; c < COUT; c += 2) {
        half2_t h;
        h.x = (half_t)accb[c];
        h.y = (half_t)accb[c + 1];
        *(half2_t*)(zrow + c) = h;
    }
}

struct GArgs {
    const int *rp0, *rp1, *rp2;
    const half_t *Z0, *Z1, *Z2;
    float *H0, *H1, *H2;
    int n0, n1, n2;
    int base1, base2;
};

// CSR gather, 2 interleaved row-chains x 4-edge unroll (8 Z-loads in flight / thread)
__global__ __launch_bounds__(256) void gather32(GArgs A, const int2* __restrict__ ecv)
{
    int bid = blockIdx.x;
    int d = (bid >= A.base1 ? 1 : 0) + (bid >= A.base2 ? 1 : 0);
    int bb = d == 0 ? 0 : (d == 1 ? A.base1 : A.base2);
    int nd = d == 0 ? A.n0 : (d == 1 ? A.n1 : A.n2);
    const int* rowptr = d == 0 ? A.rp0 : (d == 1 ? A.rp1 : A.rp2);
    const half_t* Z   = d == 0 ? A.Z0  : (d == 1 ? A.Z1  : A.Z2);
    float* H          = d == 0 ? A.H0  : (d == 1 ? A.H1  : A.H2);
    int tid = (bid - bb) * 256 + threadIdx.x;
    int pr = tid >> 3, lane = tid & 7;
    int r0 = pr * 2, r1 = r0 + 1;
    if (r0 >= nd) return;
    int s0 = rowptr[r0], e0 = rowptr[r0 + 1];
    int s1 = 0, e1 = 0;
    if (r1 < nd) { s1 = rowptr[r1]; e1 = rowptr[r1 + 1]; }
    float ax0 = 0.f, ay0 = 0.f, az0 = 0.f, aw0 = 0.f;
    float ax1 = 0.f, ay1 = 0.f, az1 = 0.f, aw1 = 0.f;
    int i0 = s0, i1 = s1;
    // 4-edge lockstep main loop: 8 independent ecv loads -> 8 independent Z loads
    while (i0 + 4 <= e0 && i1 + 4 <= e1) {
        int2 c0a = ecv[i0];     int2 c0b = ecv[i0 + 1];
        int2 c0c = ecv[i0 + 2]; int2 c0d = ecv[i0 + 3];
        int2 c1a = ecv[i1];     int2 c1b = ecv[i1 + 1];
        int2 c1c = ecv[i1 + 2]; int2 c1d = ecv[i1 + 3];
        half4_t z0a = *(const half4_t*)(Z + (size_t)c0a.x * 32 + lane * 4);
        half4_t z0b = *(const half4_t*)(Z + (size_t)c0b.x * 32 + lane * 4);
        half4_t z0c = *(const half4_t*)(Z + (size_t)c0c.x * 32 + lane * 4);
        half4_t z0d = *(const half4_t*)(Z + (size_t)c0d.x * 32 + lane * 4);
        half4_t z1a = *(const half4_t*)(Z + (size_t)c1a.x * 32 + lane * 4);
        half4_t z1b = *(const half4_t*)(Z + (size_t)c1b.x * 32 + lane * 4);
        half4_t z1c = *(const half4_t*)(Z + (size_t)c1c.x * 32 + lane * 4);
        half4_t z1d = *(const half4_t*)(Z + (size_t)c1d.x * 32 + lane * 4);
        float v0a = __int_as_float(c0a.y), v0b = __int_as_float(c0b.y);
        float v0c = __int_as_float(c0c.y), v0d = __int_as_float(c0d.y);
        float v1a = __int_as_float(c1a.y), v1b = __int_as_float(c1b.y);
        float v1c = __int_as_float(c1c.y), v1d = __int_as_float(c1d.y);
        ax0 = fmaf(v0a, (float)z0a.x, ax0); ay0 = fmaf(v0a, (float)z0a.y, ay0);
        az0 = fmaf(v0a, (float)z0a.z, az0); aw0 = fmaf(v0a, (float)z0a.w, aw0);
        ax0 = fmaf(v0b, (float)z0b.x, ax0); ay0 = fmaf(v0b, (float)z0b.y, ay0);
        az0 = fmaf(v0b, (float)z0b.z, az0); aw0 = fmaf(v0b, (float)z0b.w, aw0);
        ax0 = fmaf(v0c, (float)z0c.x, ax0); ay0 = fmaf(v0c, (float)z0c.y, ay0);
        az0 = fmaf(v0c, (float)z0c.z, az0); aw0 = fmaf(v0c, (float)z0c.w, aw0);
        ax0 = fmaf(v0d, (float)z0d.x, ax0); ay0 = fmaf(v0d, (float)z0d.y, ay0);
        az0 = fmaf(v0d, (float)z0d.z, az0); aw0 = fmaf(v0d, (float)z0d.w, aw0);
        ax1 = fmaf(v1a, (float)z1a.x, ax1); ay1 = fmaf(v1a, (float)z1a.y, ay1);
        az1 = fmaf(v1a, (float)z1a.z, az1); aw1 = fmaf(v1a, (float)z1a.w, aw1);
        ax1 = fmaf(v1b, (float)z1b.x, ax1); ay1 = fmaf(v1b, (float)z1b.y, ay1);
        az1 = fmaf(v1b, (float)z1b.z, az1); aw1 = fmaf(v1b, (float)z1b.w, aw1);
        ax1 = fmaf(v1c, (float)z1c.x, ax1); ay1 = fmaf(v1c, (float)z1c.y, ay1);
        az1 = fmaf(v1c, (float)z1c.z, az1); aw1 = fmaf(v1c, (float)z1c.w, aw1);
        ax1 = fmaf(v1d, (float)z1d.x, ax1); ay1 = fmaf(v1d, (float)z1d.y, ay1);
        az1 = fmaf(v1d, (float)z1d.z, az1); aw1 = fmaf(v1d, (float)z1d.w, aw1);
        i0 += 4; i1 += 4;
    }
    // 1-edge lockstep remainder
    while (i0 < e0 && i1 < e1) {
        int2 c0 = ecv[i0]; int2 c1 = ecv[i1];
        half4_t z0 = *(const half4_t*)(Z + (size_t)c0.x * 32 + lane * 4);
        half4_t z1 = *(const half4_t*)(Z + (size_t)c1.x * 32 + lane * 4);
        float v0 = __int_as_float(c0.y), v1 = __int_as_float(c1.y);
        ax0 = fmaf(v0, (float)z0.x, ax0); ay0 = fmaf(v0, (float)z0.y, ay0);
        az0 = fmaf(v0, (float)z0.z, az0); aw0 = fmaf(v0, (float)z0.w, aw0);
        ax1 = fmaf(v1, (float)z1.x, ax1); ay1 = fmaf(v1, (float)z1.y, ay1);
        az1 = fmaf(v1, (float)z1.z, az1); aw1 = fmaf(v1, (float)z1.w, aw1);
        i0++; i1++;
    }
    // row-0 tail: 4-edge then scalar
    for (; i0 + 4 <= e0; i0 += 4) {
        int2 c0a = ecv[i0];     int2 c0b = ecv[i0 + 1];
        int2 c0c = ecv[i0 + 2]; int2 c0d = ecv[i0 + 3];
        half4_t z0a = *(const half4_t*)(Z + (size_t)c0a.x * 32 + lane * 4);
        half4_t z0b = *(const half4_t*)(Z + (size_t)c0b.x * 32 + lane * 4);
        half4_t z0c = *(const half4_t*)(Z + (size_t)c0c.x * 32 + lane * 4);
        half4_t z0d = *(const half4_t*)(Z + (size_t)c0d.x * 32 + lane * 4);
        float v0a = __int_as_float(c0a.y), v0b = __int_as_float(c0b.y);
        float v0c = __int_as_float(c0c.y), v0d = __int_as_float(c0d.y);
        ax0 = fmaf(v0a, (float)z0a.x, ax0); ay0 = fmaf(v0a, (float)z0a.y, ay0);
        az0 = fmaf(v0a, (float)z0a.z, az0); aw0 = fmaf(v0a, (float)z0a.w, aw0);
        ax0 = fmaf(v0b, (float)z0b.x, ax0); ay0 = fmaf(v0b, (float)z0b.y, ay0);
        az0 = fmaf(v0b, (float)z0b.z, az0); aw0 = fmaf(v0b, (float)z0b.w, aw0);
        ax0 = fmaf(v0c, (float)z0c.x, ax0); ay0 = fmaf(v0c, (float)z0c.y, ay0);
        az0 = fmaf(v0c, (float)z0c.z, az0); aw0 = fmaf(v0c, (float)z0c.w, aw0);
        ax0 = fmaf(v0d, (float)z0d.x, ax0); ay0 = fmaf(v0d, (float)z0d.y, ay0);
        az0 = fmaf(v0d, (float)z0d.z, az0); aw0 = fmaf(v0d, (float)z0d.w, aw0);
    }
    for (; i0 < e0; i0++) {
        int2 c0 = ecv[i0];
        half4_t z0 = *(const half4_t*)(Z + (size_t)c0.x * 32 + lane * 4);
        float v0 = __int_as_float(c0.y);
        ax0 = fmaf(v0, (float)z0.x, ax0); ay0 = fmaf(v0, (float)z0.y, ay0);
        az0 = fmaf(v0, (float)z0.z, az0); aw0 = fmaf(v0, (float)z0.w, aw0);
    }
    // row-1 tail: 4-edge then scalar
    for (; i1 + 4 <= e1; i1 += 4) {
        int2 c1a = ecv[i1];     int2 c1b = ecv[i1 + 1];
        int2 c1c = ecv[i1 + 2]; int2 c1d = ecv[i1 + 3];
        half4_t z1a = *(const half4_t*)(Z + (size_t)c1a.x * 32 + lane * 4);
        half4_t z1b = *(const half4_t*)(Z + (size_t)c1b.x * 32 + lane * 4);
        half4_t z1c = *(const half4_t*)(Z + (size_t)c1c.x * 32 + lane * 4);
        half4_t z1d = *(const half4_t*)(Z + (size_t)c1d.x * 32 + lane * 4);
        float v1a = __int_as_float(c1a.y), v1b = __int_as_float(c1b.y);
        float v1c = __int_as_float(c1c.y), v1d = __int_as_float(c1d.y);
        ax1 = fmaf(v1a, (float)z1a.x, ax1); ay1 = fmaf(v1a, (float)z1a.y, ay1);
        az1 = fmaf(v1a, (float)z1a.z, az1); aw1 = fmaf(v1a, (float)z1a.w, aw1);
        ax1 = fmaf(v1b, (float)z1b.x, ax1); ay1 = fmaf(v1b, (float)z1b.y, ay1);
        az1 = fmaf(v1b, (float)z1b.z, az1); aw1 = fmaf(v1b, (float)z1b.w, aw1);
        ax1 = fmaf(v1c, (float)z1c.x, ax1); ay1 = fmaf(v1c, (float)z1c.y, ay1);
        az1 = fmaf(v1c, (float)z1c.z, az1); aw1 = fmaf(v1c, (float)z1c.w, aw1);
        ax1 = fmaf(v1d, (float)z1d.x, ax1); ay1 = fmaf(v1d, (float)z1d.y, ay1);
        az1 = fmaf(v1d, (float)z1d.z, az1); aw1 = fmaf(v1d, (float)z1d.w, aw1);
    }
    for (; i1 < e1; i1++) {
        int2 c1 = ecv[i1];
        half4_t z1 = *(const half4_t*)(Z + (size_t)c1.x * 32 + lane * 4);
        float v1 = __int_as_float(c1.y);
        ax1 = fmaf(v1, (float)z1.x, ax1); ay1 = fmaf(v1, (float)z1.y, ay1);
        az1 = fmaf(v1, (float)z1.z, az1); aw1 = fmaf(v1, (float)z1.w, aw1);
    }
    float4* hp0 = (float4*)(H + (size_t)r0 * 32 + lane * 4);
    float4 h0 = *hp0;
    h0.x += ax0; h0.y += ay0; h0.z += az0; h0.w += aw0;
    *hp0 = h0;
    if (r1 < nd) {
        float4* hp1 = (float4*)(H + (size_t)r1 * 32 + lane * 4);
        float4 h1 = *hp1;
        h1.x += ax1; h1.y += ay1; h1.z += az1; h1.w += aw1;
        *hp1 = h1;
    }
}

// C=10 final gather: Z packed stride 16 halfs, H packed stride 16 floats, RMW; 4-edge unroll
__global__ __launch_bounds__(256) void gather10(GArgs A, const int2* __restrict__ ecv)
{
    int bid = blockIdx.x;
    int d = (bid >= A.base1 ? 1 : 0) + (bid >= A.base2 ? 1 : 0);
    int bb = d == 0 ? 0 : (d == 1 ? A.base1 : A.base2);
    int nd = d == 0 ? A.n0 : (d == 1 ? A.n1 : A.n2);
    const int* rowptr = d == 0 ? A.rp0 : (d == 1 ? A.rp1 : A.rp2);
    const half_t* Z   = d == 0 ? A.Z0  : (d == 1 ? A.Z1  : A.Z2);
    float* H          = d == 0 ? A.H0  : (d == 1 ? A.H1  : A.H2);
    int tid = (bid - bb) * 256 + threadIdx.x;
    int pr = tid >> 3, lane = tid & 7;
    int r0 = pr * 2, r1 = r0 + 1;
    if (r0 >= nd || lane >= 5) return;
    int s0 = rowptr[r0], e0 = rowptr[r0 + 1];
    int s1 = 0, e1 = 0;
    if (r1 < nd) { s1 = rowptr[r1]; e1 = rowptr[r1 + 1]; }
    float ax0 = 0.f, ay0 = 0.f, ax1 = 0.f, ay1 = 0.f;
    int i0 = s0, i1 = s1;
    while (i0 + 4 <= e0 && i1 + 4 <= e1) {
        int2 c0a = ecv[i0];     int2 c0b = ecv[i0 + 1];
        int2 c0c = ecv[i0 + 2]; int2 c0d = ecv[i0 + 3];
        int2 c1a = ecv[i1];     int2 c1b = ecv[i1 + 1];
        int2 c1c = ecv[i1 + 2]; int2 c1d = ecv[i1 + 3];
        half2_t z0a = *(const half2_t*)(Z + (size_t)c0a.x * 16 + lane * 2);
        half2_t z0b = *(const half2_t*)(Z + (size_t)c0b.x * 16 + lane * 2);
        half2_t z0c = *(const half2_t*)(Z + (size_t)c0c.x * 16 + lane * 2);
        half2_t z0d = *(const half2_t*)(Z + (size_t)c0d.x * 16 + lane * 2);
        half2_t z1a = *(const half2_t*)(Z + (size_t)c1a.x * 16 + lane * 2);
        half2_t z1b = *(const half2_t*)(Z + (size_t)c1b.x * 16 + lane * 2);
        half2_t z1c = *(const half2_t*)(Z + (size_t)c1c.x * 16 + lane * 2);
        half2_t z1d = *(const half2_t*)(Z + (size_t)c1d.x * 16 + lane * 2);
        float v0a = __int_as_float(c0a.y), v0b = __int_as_float(c0b.y);
        float v0c = __int_as_float(c0c.y), v0d = __int_as_float(c0d.y);
        float v1a = __int_as_float(c1a.y), v1b = __int_as_float(c1b.y);
        float v1c = __int_as_float(c1c.y), v1d = __int_as_float(c1d.y);
        ax0 = fmaf(v0a, (float)z0a.x, ax0); ay0 = fmaf(v0a, (float)z0a.y, ay0);
        ax0 = fmaf(v0b, (float)z0b.x, ax0); ay0 = fmaf(v0b, (float)z0b.y, ay0);
        ax0 = fmaf(v0c, (float)z0c.x, ax0); ay0 = fmaf(v0c, (float)z0c.y, ay0);
        ax0 = fmaf(v0d, (float)z0d.x, ax0); ay0 = fmaf(v0d, (float)z0d.y, ay0);
        ax1 = fmaf(v1a, (float)z1a.x, ax1); ay1 = fmaf(v1a, (float)z1a.y, ay1);
        ax1 = fmaf(v1b, (float)z1b.x, ax1); ay1 = fmaf(v1b, (float)z1b.y, ay1);
        ax1 = fmaf(v1c, (float)z1c.x, ax1); ay1 = fmaf(v1c, (float)z1c.y, ay1);
        ax1 = fmaf(v1d, (float)z1d.x, ax1); ay1 = fmaf(v1d, (float)z1d.y, ay1);
        i0 += 4; i1 += 4;
    }
    while (i0 < e0 && i1 < e1) {
        int2 c0 = ecv[i0]; int2 c1 = ecv[i1];
        half2_t z0 = *(const half2_t*)(Z + (size_t)c0.x * 16 + lane * 2);
        half2_t z1 = *(const half2_t*)(Z + (size_t)c1.x * 16 + lane * 2);
        float v0 = __int_as_float(c0.y), v1 = __int_as_float(c1.y);
        ax0 = fmaf(v0, (float)z0.x, ax0); ay0 = fmaf(v0, (float)z0.y, ay0);
        ax1 = fmaf(v1, (float)z1.x, ax1); ay1 = fmaf(v1, (float)z1.y, ay1);
        i0++; i1++;
    }
    for (; i0 + 4 <= e0; i0 += 4) {
        int2 c0a = ecv[i0];     int2 c0b = ecv[i0 + 1];
        int2 c0c = ecv[i0 + 2]; int2 c0d = ecv[i0 + 3];
        half2_t z0a = *(const half2_t*)(Z + (size_t)c0a.x * 16 + lane * 2);
        half2_t z0b = *(const half2_t*)(Z + (size_t)c0b.x * 16 + lane * 2);
        half2_t z0c = *(const half2_t*)(Z + (size_t)c0c.x * 16 + lane * 2);
        half2_t z0d = *(const half2_t*)(Z + (size_t)c0d.x * 16 + lane * 2);
        float v0a = __int_as_float(c0a.y), v0b = __int_as_float(c0b.y);
        float v0c = __int_as_float(c0c.y), v0d = __int_as_float(c0d.y);
        ax0 = fmaf(v0a, (float)z0a.x, ax0); ay0 = fmaf(v0a, (float)z0a.y, ay0);
        ax0 = fmaf(v0b, (float)z0b.x, ax0); ay0 = fmaf(v0b, (float)z0b.y, ay0);
        ax0 = fmaf(v0c, (float)z0c.x, ax0); ay0 = fmaf(v0c, (float)z0c.y, ay0);
        ax0 = fmaf(v0d, (float)z0d.x, ax0); ay0 = fmaf(v0d, (float)z0d.y, ay0);
    }
    for (; i0 < e0; i0++) {
        int2 c0 = ecv[i0];
        half2_t z0 = *(const half2_t*)(Z + (size_t)c0.x * 16 + lane * 2);
        float v0 = __int_as_float(c0.y);
        ax0 = fmaf(v0, (float)z0.x, ax0); ay0 = fmaf(v0, (float)z0.y, ay0);
    }
    for (; i1 + 4 <= e1; i1 += 4) {
        int2 c1a = ecv[i1];     int2 c1b = ecv[i1 + 1];
        int2 c1c = ecv[i1 + 2]; int2 c1d = ecv[i1 + 3];
        half2_t z1a = *(const half2_t*)(Z + (size_t)c1a.x * 16 + lane * 2);
        half2_t z1b = *(const half2_t*)(Z + (size_t)c1b.x * 16 + lane * 2);
        half2_t z1c = *(const half2_t*)(Z + (size_t)c1c.x * 16 + lane * 2);
        half2_t z1d = *(const half2_t*)(Z + (size_t)c1d.x * 16 + lane * 2);
        float v1a = __int_as_float(c1a.y), v1b = __int_as_float(c1b.y);
        float v1c = __int_as_float(c1c.y), v1d = __int_as_float(c1d.y);
        ax1 = fmaf(v1a, (float)z1a.x, ax1); ay1 = fmaf(v1a, (float)z1a.y, ay1);
        ax1 = fmaf(v1b, (float)z1b.x, ax1); ay1 = fmaf(v1b, (float)z1b.y, ay1);
        ax1 = fmaf(v1c, (float)z1c.x, ax1); ay1 = fmaf(v1c, (float)z1c.y, ay1);
        ax1 = fmaf(v1d, (float)z1d.x, ax1); ay1 = fmaf(v1d, (float)z1d.y, ay1);
    }
    for (; i1 < e1; i1++) {
        int2 c1 = ecv[i1];
        half2_t z1 = *(const half2_t*)(Z + (size_t)c1.x * 16 + lane * 2);
        float v1 = __int_as_float(c1.y);
        ax1 = fmaf(v1, (float)z1.x, ax1); ay1 = fmaf(v1, (float)z1.y, ay1);
    }
    float* hp0 = H + (size_t)r0 * 16 + lane * 2;
    hp0[0] += ax0; hp0[1] += ay0;
    if (r1 < nd) {
        float* hp1 = H + (size_t)r1 * 16 + lane * 2;
        hp1[0] += ax1; hp1[1] += ay1;
    }
}

struct PArgs {
    const float *H0, *H1, *H2;
    const int *bt0, *bt1, *bt2;
    int n0, n1, n2;
};

// 3*G blocks: block -> (dim, graph); batch sorted -> binary search, no atomics; H stride 16
__global__ __launch_bounds__(256) void pool_graph(PArgs A, float* __restrict__ pool, int G)
{
    int bid = blockIdx.x;
    int d = (bid >= G ? 1 : 0) + (bid >= 2 * G ? 1 : 0);
    int g = bid - d * G;
    const float* H = d == 0 ? A.H0 : (d == 1 ? A.H1 : A.H2);
    const int* batch = d == 0 ? A.bt0 : (d == 1 ? A.bt1 : A.bt2);
    int N = d == 0 ? A.n0 : (d == 1 ? A.n1 : A.n2);
    int lo = 0, hi = N;
    while (lo < hi) { int mid = (lo + hi) >> 1; if (batch[mid] < g) lo = mid + 1; else hi = mid; }
    int start = lo;
    lo = start; hi = N;
    while (lo < hi) { int mid = (lo + hi) >> 1; if (batch[mid] < g + 1) lo = mid + 1; else hi = mid; }
    int end = lo;
    int t = threadIdx.x, f = t & 15, chain = t >> 4;
    __shared__ float sd[256];
    float acc = 0.f;
    if (f < 10) {
        for (int i = start + chain; i < end; i += 16) acc += H[(size_t)i * 16 + f];
    }
    sd[t] = acc; __syncthreads();
    if (chain == 0 && f < 10) {
        float s = 0.f;
#pragma unroll
        for (int k = 0; k < 16; k++) s += sd[k * 16 + f];
        int c = end - start;
        float inv = 1.f / (float)(c > 1 ? c : 1);
        pool[(size_t)g * 30 + d * 10 + f] = s * inv;
    }
}

__global__ __launch_bounds__(256) void final_kernel(
    const float* __restrict__ pool, const float* __restrict__ Wf,
    const float* __restrict__ bfv, float* __restrict__ out, int G)
{
    int g = blockIdx.x * 256 + threadIdx.x;
    if (g >= G) return;
    float m[30];
#pragma unroll
    for (int j = 0; j < 30; j++) m[j] = pool[(size_t)g * 30 + j];
    float lg[10];
#pragma unroll
    for (int o = 0; o < 10; o++) {
        float a = bfv[o];
#pragma unroll
        for (int j = 0; j < 30; j++) a = fmaf(m[j], Wf[j * 10 + o], a);
        lg[o] = a;
    }
    float mx = lg[0];
#pragma unroll
    for (int o = 1; o < 10; o++) mx = fmaxf(mx, lg[o]);
    float s = 0.f;
#pragma unroll
    for (int o = 0; o < 10; o++) { lg[o] = __expf(lg[o] - mx); s += lg[o]; }
    float invs = 1.f / s;
#pragma unroll
    for (int o = 0; o < 10; o++) out[(size_t)g * 10 + o] = lg[o] * invs;
}

extern "C" void kernel_launch(void* const* d_in, const int* in_sizes, int n_in,
                              void* d_out, int out_size, void* d_ws, size_t ws_size,
                              hipStream_t stream)
{
    (void)n_in;
    const float* x[3]    = {(const float*)d_in[0], (const float*)d_in[1], (const float*)d_in[2]};
    const float* vals[3] = {(const float*)d_in[3], (const float*)d_in[4], (const float*)d_in[5]};
    const int* rows[3]   = {(const int*)d_in[6], (const int*)d_in[8], (const int*)d_in[10]};
    const int* cols[3]   = {(const int*)d_in[7], (const int*)d_in[9], (const int*)d_in[11]};
    const int* batch[3]  = {(const int*)d_in[12], (const int*)d_in[13], (const int*)d_in[14]};
    const float* W1[3] = {(const float*)d_in[16], (const float*)d_in[22], (const float*)d_in[28]};
    const float* b1[3] = {(const float*)d_in[17], (const float*)d_in[23], (const float*)d_in[29]};
    const float* W2[3] = {(const float*)d_in[18], (const float*)d_in[24], (const float*)d_in[30]};
    const float* b2[3] = {(const float*)d_in[19], (const float*)d_in[25], (const float*)d_in[31]};
    const float* W3[3] = {(const float*)d_in[20], (const float*)d_in[26], (const float*)d_in[32]};
    const float* b3[3] = {(const float*)d_in[21], (const float*)d_in[27], (const float*)d_in[33]};
    const float* Wf  = (const float*)d_in[34];
    const float* bfv = (const float*)d_in[35];
    float* out = (float*)d_out;

    int N[3] = {in_sizes[0] / 32, in_sizes[1] / 32, in_sizes[2] / 32};
    int E[3] = {in_sizes[3], in_sizes[4], in_sizes[5]};
    int G = out_size / 10;
    int maxN = N[0]; if (N[1] > maxN) maxN = N[1]; if (N[2] > maxN) maxN = N[2];
    int maxE = E[0]; if (E[1] > maxE) maxE = E[1]; if (E[2] > maxE) maxE = E[2];

    // union (bucket-aligned) row offsets; cols stay LOCAL everywhere
    int o1 = cdiv(N[0], RALIGN) * RALIGN;
    int o2 = o1 + cdiv(N[1], RALIGN) * RALIGN;
    int NU = o2 + N[2];
    long long EU = (long long)E[0] + E[1] + E[2];
    int NBcU = cdiv(NU, RALIGN);
    int NBmU = cdiv(NU, 1 << MSHIFT);
    size_t sumN = (size_t)N[0] + N[1] + N[2];
    size_t pN[3] = {0, (size_t)N[0], (size_t)N[0] + N[1]};
    int offsU[3] = {0, o1, o2};

    char* base = (char*)d_ws;

    // ---- batched layout ----
    // [0, regC): build stg1[EU] + stgm[EU] / compute bufA3(sumN*128B) + bufZ3(sumN*64B)
    size_t regC = al16((size_t)2 * EU * 8 > sumN * 192 ? (size_t)2 * EU * 8 : sumN * 192);
    size_t off_z3  = regC;                                  // Z3p packed: sumN*32 B
    size_t off_ecv = al16(off_z3 + sumN * 32);
    size_t off_rp  = off_ecv + (size_t)EU * 8;
    size_t off_cnt = al16(off_rp + ((size_t)NU + 1) * 4);
    size_t cnt_ints = (size_t)3 * NBmU + 1 + 256 + 258 + 256;
    size_t off_pool = al16(off_cnt + cnt_ints * 4);
    size_t need = off_pool + (size_t)G * 30 * 4;
    bool batched = (need <= ws_size);

    if (batched) {
        int2* stg1 = (int2*)base;
        int2* stgm = (int2*)(base + (size_t)EU * 8);
        float* bufA3 = (float*)base;
        half_t* bufZ3 = (half_t*)(base + sumN * 128);
        float* H3p3 = (float*)(base + sumN * 128);          // replaces Z1/Z2 region at layer 3
        half_t* Z3p3 = (half_t*)(base + off_z3);
        int2* ecv = (int2*)(base + off_ecv);
        int* rowptrU = (int*)(base + off_rp);
        int* mcnt = (int*)(base + off_cnt);
        int* mbase = mcnt + NBmU;
        int* mfront = mbase + NBmU + 1;
        int* ccnt = mfront + NBmU;
        int* cbase = ccnt + 256;
        int* cfront = cbase + 258;
        float* pool = (float*)(base + off_pool);

        // ---- ONE union build for all 3 dims ----
        Src3 S;
        S.r0 = rows[0]; S.c0 = cols[0]; S.v0 = vals[0];
        S.r1 = rows[1]; S.c1 = cols[1]; S.v1 = vals[1];
        S.r2 = rows[2]; S.c2 = cols[2]; S.v2 = vals[2];
        S.e1 = E[0]; S.e2 = E[0] + E[1]; S.etot = (int)EU;
        S.o1 = o1; S.o2 = o2;
        int ntileU = cdiv(EU, TILE_E);
        int zlenU = 3 * NBmU + 257;     // mcnt + mbase + mfront + ccnt (contiguous)
        zero_i32<<<cdiv(zlenU, 256), 256, 0, stream>>>(mcnt, zlenU);
        hist_coarse<<<ntileU, 256, 0, stream>>>(S, ccnt);
        scan_coarse<<<1, 64, 0, stream>>>(ccnt, cbase, cfront, NBcU, (int)EU);
        split_coarse<<<ntileU, 256, 0, stream>>>(S, cfront, stg1);
        hist_mid<<<ntileU, 256, 0, stream>>>(stg1, cbase, mcnt, (int)EU, NBcU);
        scan_mid_par<<<NBcU, 64, 0, stream>>>(mcnt, cbase, mbase, mfront, NBmU, (int)EU);
        split_mid<<<ntileU, 256, 0, stream>>>(stg1, cbase, mfront, stgm, (int)EU, NBcU);
        csr_sort<<<NBmU, 256, 0, stream>>>(stgm, mbase, rowptrU, ecv, NU);

        // ---- per-layer batched compute across all 3 dims ----
        int nb[3], gb[3];
        for (int d = 0; d < 3; d++) {
            nb[d] = cdiv(N[d], 256);
            gb[d] = cdiv((long long)cdiv(N[d], 2) * 8, 256);
        }
        DArgs D;
        D.in0 = x[0]; D.in1 = x[1]; D.in2 = x[2];
        D.W0 = W1[0]; D.W1 = W1[1]; D.W2 = W1[2];
        D.bb0 = b1[0]; D.bb1 = b1[1]; D.bb2 = b1[2];
        D.H0 = bufA3 + pN[0] * 32; D.H1 = bufA3 + pN[1] * 32; D.H2 = bufA3 + pN[2] * 32;
        D.Z0 = bufZ3 + pN[0] * 32; D.Z1 = bufZ3 + pN[1] * 32; D.Z2 = bufZ3 + pN[2] * 32;
        D.n0 = N[0]; D.n1 = N[1]; D.n2 = N[2];
        D.base1 = nb[0]; D.base2 = nb[0] + nb[1];
        int nbsum = nb[0] + nb[1] + nb[2];

        GArgs Gg;
        Gg.rp0 = rowptrU + offsU[0]; Gg.rp1 = rowptrU + offsU[1]; Gg.rp2 = rowptrU + offsU[2];
        Gg.Z0 = D.Z0; Gg.Z1 = D.Z1; Gg.Z2 = D.Z2;
        Gg.H0 = D.H0; Gg.H1 = D.H1; Gg.H2 = D.H2;
        Gg.n0 = N[0]; Gg.n1 = N[1]; Gg.n2 = N[2];
        Gg.base1 = gb[0]; Gg.base2 = gb[0] + gb[1];
        int gbsum = gb[0] + gb[1] + gb[2];

        dense_kernel<32, false, 32, 32><<<nbsum, 256, 0, stream>>>(D);
        gather32<<<gbsum, 256, 0, stream>>>(Gg, ecv);
        D.in0 = D.H0; D.in1 = D.H1; D.in2 = D.H2;
        D.W0 = W2[0]; D.W1 = W2[1]; D.W2 = W2[2];
        D.bb0 = b2[0]; D.bb1 = b2[1]; D.bb2 = b2[2];
        dense_kernel<32, true, 32, 32><<<nbsum, 256, 0, stream>>>(D);
        gather32<<<gbsum, 256, 0, stream>>>(Gg, ecv);
        // layer 3: packed H (stride 16 f32, in old Z region) + packed Z (stride 16 half)
        DArgs D3 = D;
        D3.W0 = W3[0]; D3.W1 = W3[1]; D3.W2 = W3[2];
        D3.bb0 = b3[0]; D3.bb1 = b3[1]; D3.bb2 = b3[2];
        D3.H0 = H3p3 + pN[0] * 16; D3.H1 = H3p3 + pN[1] * 16; D3.H2 = H3p3 + pN[2] * 16;
        D3.Z0 = Z3p3 + pN[0] * 16; D3.Z1 = Z3p3 + pN[1] * 16; D3.Z2 = Z3p3 + pN[2] * 16;
        dense_kernel<10, true, 16, 16><<<nbsum, 256, 0, stream>>>(D3);
        GArgs G10 = Gg;
        G10.Z0 = D3.Z0; G10.Z1 = D3.Z1; G10.Z2 = D3.Z2;
        G10.H0 = D3.H0; G10.H1 = D3.H1; G10.H2 = D3.H2;
        gather10<<<gbsum, 256, 0, stream>>>(G10, ecv);
        PArgs P;
        P.H0 = D3.H0; P.H1 = D3.H1; P.H2 = D3.H2;
        P.bt0 = batch[0]; P.bt1 = batch[1]; P.bt2 = batch[2];
        P.n0 = N[0]; P.n1 = N[1]; P.n2 = N[2];
        pool_graph<<<3 * G, 256, 0, stream>>>(P, pool, G);
        final_kernel<<<cdiv(G, 256), 256, 0, stream>>>(pool, Wf, bfv, out, G);
    } else {
        // ---- fallback: per-dim build + compute (R5-equivalent layout), same kernels ----
        int maxNBm = cdiv(maxN, 1 << MSHIFT);
        float* bufA = (float*)base;
        half_t* bufZh = (half_t*)(base + (size_t)maxN * 128);
        float* H3p = (float*)(base + (size_t)maxN * 128);
        half_t* Z3p = (half_t*)(base + (size_t)maxN * 128 + (size_t)maxN * 64);
        float* pool = (float*)(base + (size_t)maxN * 256);
        int2* ecv = (int2*)(base + al16((size_t)maxN * 256 + (size_t)G * 30 * 4));
        int* rowptr = (int*)(ecv + maxE);
        int* mcnt = rowptr + (maxN + 1);
        int* mbase = mcnt + maxNBm;
        int* mfront = mbase + (maxNBm + 1);
        int* ccnt = mfront + maxNBm;
        int* cbase = ccnt + 256;
        int* cfront = cbase + 258;
        int2* stg1 = (int2*)bufA;
        int2* stgm = (int2*)(base + (size_t)maxN * 128);
        int zlen = 3 * maxNBm + 257;
        for (int d = 0; d < 3; d++) {
            int n = N[d], e = E[d];
            int NBc = cdiv(n, RALIGN);
            int NBm = cdiv(n, 1 << MSHIFT);
            int ntile = cdiv(e, TILE_E);
            int nb = cdiv(n, 256);
            int gbl = cdiv((long long)cdiv(n, 2) * 8, 256);
            Src3 S;
            S.r0 = rows[d]; S.c0 = cols[d]; S.v0 = vals[d];
            S.r1 = rows[d]; S.c1 = cols[d]; S.v1 = vals[d];
            S.r2 = rows[d]; S.c2 = cols[d]; S.v2 = vals[d];
            S.e1 = e; S.e2 = e; S.etot = e; S.o1 = 0; S.o2 = 0;
            zero_i32<<<cdiv(zlen, 256), 256, 0, stream>>>(mcnt, zlen);
            hist_coarse<<<ntile, 256, 0, stream>>>(S, ccnt);
            scan_coarse<<<1, 64, 0, stream>>>(ccnt, cbase, cfront, NBc, e);
            split_coarse<<<ntile, 256, 0, stream>>>(S, cfront, stg1);
            hist_mid<<<ntile, 256, 0, stream>>>(stg1, cbase, mcnt, e, NBc);
            scan_mid_par<<<NBc, 64, 0, stream>>>(mcnt, cbase, mbase, mfront, NBm, e);
            split_mid<<<ntile, 256, 0, stream>>>(stg1, cbase, mfront, stgm, e, NBc);
            csr_sort<<<NBm, 256, 0, stream>>>(stgm, mbase, rowptr, ecv, n);

            DArgs D;
            D.in0 = x[d]; D.in1 = x[d]; D.in2 = x[d];
            D.W0 = W1[d]; D.W1 = W1[d]; D.W2 = W1[d];
            D.bb0 = b1[d]; D.bb1 = b1[d]; D.bb2 = b1[d];
            D.H0 = bufA; D.H1 = bufA; D.H2 = bufA;
            D.Z0 = bufZh; D.Z1 = bufZh; D.Z2 = bufZh;
            D.n0 = n; D.n1 = n; D.n2 = n;
            D.base1 = nb; D.base2 = nb;
            GArgs Gg;
            Gg.rp0 = rowptr; Gg.rp1 = rowptr; Gg.rp2 = rowptr;
            Gg.Z0 = bufZh; Gg.Z1 = bufZh; Gg.Z2 = bufZh;
            Gg.H0 = bufA; Gg.H1 = bufA; Gg.H2 = bufA;
            Gg.n0 = n; Gg.n1 = n; Gg.n2 = n;
            Gg.base1 = gbl; Gg.base2 = gbl;
            dense_kernel<32, false, 32, 32><<<nb, 256, 0, stream>>>(D);
            gather32<<<gbl, 256, 0, stream>>>(Gg, ecv);
            D.in0 = bufA; D.in1 = bufA; D.in2 = bufA;
            D.W0 = W2[d]; D.W1 = W2[d]; D.W2 = W2[d];
            D.bb0 = b2[d]; D.bb1 = b2[d]; D.bb2 = b2[d];
            dense_kernel<32, true, 32, 32><<<nb, 256, 0, stream>>>(D);
            gather32<<<gbl, 256, 0, stream>>>(Gg, ecv);
            DArgs D3 = D;
            D3.W0 = W3[d]; D3.W1 = W3[d]; D3.W2 = W3[d];
            D3.bb0 = b3[d]; D3.bb1 = b3[d]; D3.bb2 = b3[d];
            D3.H0 = H3p; D3.H1 = H3p; D3.H2 = H3p;
            D3.Z0 = Z3p; D3.Z1 = Z3p; D3.Z2 = Z3p;
            dense_kernel<10, true, 16, 16><<<nb, 256, 0, stream>>>(D3);
            GArgs G10 = Gg;
            G10.Z0 = Z3p; G10.Z1 = Z3p; G10.Z2 = Z3p;
            G10.H0 = H3p; G10.H1 = H3p; G10.H2 = H3p;
            gather10<<<gbl, 256, 0, stream>>>(G10, ecv);
            PArgs P;
            P.H0 = H3p; P.H1 = H3p; P.H2 = H3p;
            P.bt0 = batch[d]; P.bt1 = batch[d]; P.bt2 = batch[d];
            P.n0 = n; P.n1 = n; P.n2 = n;
            // G-block launch => in-kernel d==0; offset pool base by d*10 so each dim
            // lands in its [g*30 + d*10 + f] slot
            pool_graph<<<G, 256, 0, stream>>>(P, pool + (size_t)d * 10, G);
        }
        final_kernel<<<cdiv(G, 256), 256, 0, stream>>>(pool, Wf, bfv, out, G);
    }
}